// Round 4
// baseline (1280.529 us; speedup 1.0000x reference)
//
#include <hip/hip_runtime.h>
#include <hip/hip_bf16.h>

#define N_NODES 20000
#define N_EDGES 100000
#define N_LAYERS 25
#define NPAD 20096   // 157*128
#define EPS_BN 1e-5f
#define LOG2E 1.44269504088896340736f

typedef short short8 __attribute__((ext_vector_type(8)));
typedef float floatx4 __attribute__((ext_vector_type(4)));

template <int PAT>
__device__ __forceinline__ float swz(float v) {
  return __int_as_float(__builtin_amdgcn_ds_swizzle(__float_as_int(v), PAT));
}

// attention edge weight: leaky-relu, per-head (32-lane) dot with att, exp2
__device__ __forceinline__ float edge_w(float xlv, float w, float wev, float xrn,
                                        float att2v) {
  float v = xlv + fmaf(w, wev, xrn);
  float lk = fmaxf(v, 0.2f * v);
  float p = lk * att2v;
  p += swz<0x041F>(p);
  p += swz<0x081F>(p);
  p += swz<0x101F>(p);
  p += swz<0x201F>(p);
  p += swz<0x401F>(p);
  return __builtin_amdgcn_exp2f(p);  // softmax shift-invariant; logits small
}

// ---------------- CSR build ----------------
__global__ __launch_bounds__(256) void count_kernel(const int* __restrict__ ei,
                                                    int* __restrict__ cnt) {
  int idx = blockIdx.x * 256 + threadIdx.x;
  if (idx >= N_LAYERS * N_EDGES) return;
  int l = idx / N_EDGES, e = idx - l * N_EDGES;
  int dst = ei[(size_t)l * 2 * N_EDGES + N_EDGES + e];
  atomicAdd(&cnt[l * (N_NODES + 1) + dst], 1);
}

__global__ __launch_bounds__(1024) void scan_kernel(int* __restrict__ rowptr,
                                                    int* __restrict__ fillptr) {
  int l = blockIdx.x, t = threadIdx.x;
  int lane = t & 63, wv = t >> 6;  // 16 waves
  __shared__ int wsum[16];
  __shared__ int carry_s;
  if (t == 0) carry_s = 0;
  __syncthreads();
  int base = l * (N_NODES + 1);
  for (int c0 = 0; c0 < N_NODES; c0 += 1024) {
    int i = c0 + t;
    int v = (i < N_NODES) ? rowptr[base + i] : 0;
    int sc = v;
#pragma unroll
    for (int off = 1; off < 64; off <<= 1) {
      int u = __shfl_up(sc, off);
      if (lane >= off) sc += u;
    }
    if (lane == 63) wsum[wv] = sc;
    __syncthreads();
    if (wv == 0) {
      int xx = (lane < 16) ? wsum[lane] : 0;
#pragma unroll
      for (int off = 1; off < 16; off <<= 1) {
        int u = __shfl_up(xx, off);
        if (lane >= off) xx += u;
      }
      if (lane < 16) wsum[lane] = xx;
    }
    __syncthreads();
    int boff = carry_s + (wv > 0 ? wsum[wv - 1] : 0);
    int excl = boff + sc - v;
    if (i < N_NODES) { rowptr[base + i] = excl; fillptr[l * N_NODES + i] = excl; }
    int tot = wsum[15];
    __syncthreads();
    if (t == 0) carry_s += tot;
    __syncthreads();
  }
  if (t == 0) rowptr[base + N_NODES] = carry_s;
}

__global__ __launch_bounds__(256) void fill_kernel(const int* __restrict__ ei,
                                                   const float* __restrict__ ew,
                                                   int* __restrict__ fillptr,
                                                   int2* __restrict__ ep) {
  int idx = blockIdx.x * 256 + threadIdx.x;
  if (idx >= N_LAYERS * N_EDGES) return;
  int l = idx / N_EDGES, e = idx - l * N_EDGES;
  int src = ei[(size_t)l * 2 * N_EDGES + e];
  int dst = ei[(size_t)l * 2 * N_EDGES + N_EDGES + e];
  int pos = atomicAdd(&fillptr[l * N_NODES + dst], 1);
  int2 rec;
  rec.x = src;
  rec.y = __float_as_int(ew[(size_t)l * N_EDGES + e]);
  ep[(size_t)l * N_EDGES + pos] = rec;
}

// ---------------- precompute xl = x @ Wl + bl, [L][N][64] ----------------
__global__ __launch_bounds__(256) void xl_kernel(const float* __restrict__ x,
                                                 const float* __restrict__ Wl,
                                                 const float* __restrict__ bl,
                                                 float* __restrict__ xl) {
  int wid = blockIdx.x * 4 + (threadIdx.x >> 6);
  int lane = threadIdx.x & 63;
  int l = wid / N_NODES, n = wid - l * N_NODES;
  float acc = bl[l * 64 + lane];
#pragma unroll
  for (int k = 0; k < 5; k++)
    acc = fmaf(x[n * 5 + k], Wl[(l * 5 + k) * 64 + lane], acc);
  xl[(size_t)wid * 64 + lane] = acc;
}

// ---------------- fused GAT layer + BN stats (1 wave per (layer,node)) -------
__global__ __launch_bounds__(256) void attn_kernel(
    const float* __restrict__ x, const float* __restrict__ xl,
    const int* __restrict__ rowptr, const int2* __restrict__ ep,
    const float* __restrict__ Wr, const float* __restrict__ br,
    const float* __restrict__ We, const float* __restrict__ att,
    const float* __restrict__ cbias, float* __restrict__ out_pre,
    float* __restrict__ gsum, float* __restrict__ gsumsq) {
  int wv = threadIdx.x >> 6;
  int wid = blockIdx.x * 4 + wv;
  int lane = threadIdx.x & 63;
  int l = wid / N_NODES, n = wid - l * N_NODES;

  const float* xlb = xl + (size_t)l * N_NODES * 64;
  float wev = We[l * 64 + lane];
  float att2v = att[l * 64 + lane] * LOG2E;

  // own-node: xr (recomputed) and xl (from precompute)
  float xrn = br[l * 64 + lane];
#pragma unroll
  for (int k = 0; k < 5; k++)
    xrn = fmaf(x[n * 5 + k], Wr[(l * 5 + k) * 64 + lane], xrn);
  float xln = xlb[n * 64 + lane];

  int start = __builtin_amdgcn_readfirstlane(rowptr[l * (N_NODES + 1) + n]);
  int end   = __builtin_amdgcn_readfirstlane(rowptr[l * (N_NODES + 1) + n + 1]);
  int cnt = end - start;
  int cnt64 = cnt < 64 ? cnt : 64;

  // batch-load up to 64 edge records: lane e holds ep[start+e]; others 0
  int rsrc = 0, rw = 0;
  if (lane < cnt64) {
    int2 rec = ep[(size_t)l * N_EDGES + start + lane];
    rsrc = rec.x;
    rw = rec.y;
  }

  float ssum = 0.f, acc = 0.f, ewsum = 0.f;

  // 1-deep prefetch; (e+1)&63 always indexes a lane holding a valid row id
  int s0 = __builtin_amdgcn_readlane(rsrc, 0);
  float xv = xlb[s0 * 64 + lane];
  for (int e = 0; e < cnt64; e++) {
    int sn = __builtin_amdgcn_readlane(rsrc, (e + 1) & 63);
    float xnext = xlb[sn * 64 + lane];
    float w = __int_as_float(__builtin_amdgcn_readlane(rw, e));
    float pe = edge_w(xv, w, wev, xrn, att2v);
    ssum += pe;
    acc = fmaf(xv, pe, acc);
    ewsum += w;
    xv = xnext;
  }
  // rare overflow path: in-degree > 64
  for (int e = start + 64; e < end; e++) {
    int2 rec = ep[(size_t)l * N_EDGES + e];
    int s = __builtin_amdgcn_readfirstlane(rec.x);
    float w = __int_as_float(__builtin_amdgcn_readfirstlane(rec.y));
    float xg = xlb[s * 64 + lane];
    float pe = edge_w(xg, w, wev, xrn, att2v);
    ssum += pe;
    acc = fmaf(xg, pe, acc);
    ewsum += w;
  }
  // self loop: attr = mean of incoming edge attrs
  {
    float w = ewsum * __builtin_amdgcn_rcpf(fmaxf((float)cnt, 1.f));
    float pe = edge_w(xln, w, wev, xrn, att2v);
    ssum += pe;
    acc = fmaf(xln, pe, acc);
  }
  float outv = acc * __builtin_amdgcn_rcpf(ssum * (float)(cnt + 1));
  float o2 = outv + __shfl_xor(outv, 32);

  __shared__ float ssm[4][32], ssq[4][32];
  float oval = 0.f;
  if (lane < 32) {
    oval = 0.5f * o2 + cbias[l * 32 + lane];
    out_pre[((size_t)l * N_NODES + n) * 32 + lane] = oval;
    ssm[wv][lane] = oval;
    ssq[wv][lane] = oval * oval;
  }
  __syncthreads();
  if (threadIdx.x < 32) {
    int c = threadIdx.x;
    float a = ssm[0][c] + ssm[1][c] + ssm[2][c] + ssm[3][c];
    float b = ssq[0][c] + ssq[1][c] + ssq[2][c] + ssq[3][c];
    atomicAdd(&gsum[l * 32 + c], a);
    atomicAdd(&gsumsq[l * 32 + c], b);
  }
}

// ---------------- normalize + leaky relu -> bf16 [L][NPAD][32] ----------------
__global__ __launch_bounds__(256) void norm_kernel(const float* __restrict__ out_pre,
                                                   const float* __restrict__ gsum,
                                                   const float* __restrict__ gsumsq,
                                                   const float* __restrict__ gamma,
                                                   const float* __restrict__ beta,
                                                   __hip_bfloat16* __restrict__ hn) {
  int idx = blockIdx.x * 256 + threadIdx.x;  // < 25*20000*32
  int l = idx / (N_NODES * 32);
  int rem = idx - l * (N_NODES * 32);
  int n = rem >> 5, c = rem & 31;
  float mu = gsum[l * 32 + c] * (1.f / N_NODES);
  float var = gsumsq[l * 32 + c] * (1.f / N_NODES) - mu * mu;
  float v = out_pre[idx];
  v = gamma[l * 32 + c] * (v - mu) * rsqrtf(var + EPS_BN) + beta[l * 32 + c];
  v = v > 0.f ? v : 0.01f * v;
  hn[((size_t)l * NPAD + n) * 32 + c] = (__hip_bfloat16)v;
}

// ---------------- W1 -> bf16 transposed [896][800] ----------------
__global__ void w1t_kernel(const float* __restrict__ W1, __hip_bfloat16* __restrict__ W1bT) {
  __shared__ float tile[32][33];
  int j0 = blockIdx.x * 32, k0 = blockIdx.y * 32;
  int tx = threadIdx.x, ty = threadIdx.y;  // (32,8)
#pragma unroll
  for (int i = 0; i < 4; i++) {
    int k = k0 + ty + i * 8, j = j0 + tx;
    tile[ty + i * 8][tx] = (j < 800) ? W1[k * 800 + j] : 0.f;
  }
  __syncthreads();
#pragma unroll
  for (int i = 0; i < 4; i++) {
    int j = j0 + ty + i * 8, k = k0 + tx;
    W1bT[(size_t)j * 800 + k] = (__hip_bfloat16)tile[tx][ty + i * 8];
  }
}

// ---------------- GEMM1: h[NPAD x 800] @ W1 -> relu -> bf16 h1 ----------------
__global__ __launch_bounds__(256) void gemm1_kernel(const short* __restrict__ hn,
                                                    const short* __restrict__ W1bT,
                                                    const float* __restrict__ b1,
                                                    __hip_bfloat16* __restrict__ h1b) {
  __shared__ __align__(16) short As[128 * 40];
  __shared__ __align__(16) short Bs[128 * 40];
  int t = threadIdx.x;
  int n0 = blockIdx.x * 128, m0 = blockIdx.y * 128;
  int wave = t >> 6, lane = t & 63;
  int wr = wave >> 1, wc = wave & 1;
  int mrow = lane & 15, quad = lane >> 4;
  floatx4 acc[4][4];
#pragma unroll
  for (int i = 0; i < 4; i++)
#pragma unroll
    for (int j = 0; j < 4; j++) acc[i][j] = (floatx4){0.f, 0.f, 0.f, 0.f};

  for (int kt = 0; kt < 25; kt++) {
#pragma unroll
    for (int i = 0; i < 2; i++) {
      int q = t + i * 256;
      int r = q >> 2, sub = q & 3;
      const int4* gA = (const int4*)(hn + ((size_t)kt * NPAD + m0 + r) * 32 + sub * 8);
      *(int4*)(&As[r * 40 + sub * 8]) = *gA;
      const int4* gB = (const int4*)(W1bT + (size_t)(n0 + r) * 800 + kt * 32 + sub * 8);
      *(int4*)(&Bs[r * 40 + sub * 8]) = *gB;
    }
    __syncthreads();
    short8 af[4], bfr[4];
#pragma unroll
    for (int i = 0; i < 4; i++)
      af[i] = *(const short8*)(&As[(wr * 64 + i * 16 + mrow) * 40 + quad * 8]);
#pragma unroll
    for (int j = 0; j < 4; j++)
      bfr[j] = *(const short8*)(&Bs[(wc * 64 + j * 16 + mrow) * 40 + quad * 8]);
#pragma unroll
    for (int i = 0; i < 4; i++)
#pragma unroll
      for (int j = 0; j < 4; j++)
        acc[i][j] = __builtin_amdgcn_mfma_f32_16x16x32_bf16(af[i], bfr[j], acc[i][j], 0, 0, 0);
    __syncthreads();
  }

#pragma unroll
  for (int i = 0; i < 4; i++) {
#pragma unroll
    for (int j = 0; j < 4; j++) {
#pragma unroll
      for (int r = 0; r < 4; r++) {
        int row = m0 + wr * 64 + i * 16 + quad * 4 + r;
        int col = n0 + wc * 64 + j * 16 + mrow;
        if (col < 800) {
          float v = acc[i][j][r] + b1[col];
          v = fmaxf(v, 0.f);
          h1b[(size_t)row * 800 + col] = (__hip_bfloat16)v;
        }
      }
    }
  }
}

// ---------------- GEMM2: h1[20000 x 800] @ W2[800 x 5] + b2 ----------------
__global__ __launch_bounds__(256) void gemm2_kernel(const __hip_bfloat16* __restrict__ h1b,
                                                    const float* __restrict__ W2,
                                                    const float* __restrict__ b2,
                                                    float* __restrict__ out) {
  int wid = blockIdx.x * 4 + (threadIdx.x >> 6);
  int lane = threadIdx.x & 63;
  if (wid >= N_NODES) return;
  const __hip_bfloat16* row = h1b + (size_t)wid * 800;
  float a[5] = {0.f, 0.f, 0.f, 0.f, 0.f};
  for (int k = lane * 2; k < 800; k += 128) {
    float a0 = (float)row[k], a1 = (float)row[k + 1];
#pragma unroll
    for (int j = 0; j < 5; j++) a[j] += a0 * W2[k * 5 + j] + a1 * W2[(k + 1) * 5 + j];
  }
#pragma unroll
  for (int j = 0; j < 5; j++) {
    a[j] += __shfl_xor(a[j], 32);
    a[j] += __shfl_xor(a[j], 16);
    a[j] += __shfl_xor(a[j], 8);
    a[j] += __shfl_xor(a[j], 4);
    a[j] += __shfl_xor(a[j], 2);
    a[j] += __shfl_xor(a[j], 1);
  }
  if (lane == 0) {
#pragma unroll
    for (int j = 0; j < 5; j++) out[wid * 5 + j] = a[j] + b2[j];
  }
}

extern "C" void kernel_launch(void* const* d_in, const int* in_sizes, int n_in,
                              void* d_out, int out_size, void* d_ws, size_t ws_size,
                              hipStream_t stream) {
  const float* x    = (const float*)d_in[0];
  const int*   ei   = (const int*)d_in[1];
  const float* ew   = (const float*)d_in[2];
  const float* Wl   = (const float*)d_in[3];
  const float* bl   = (const float*)d_in[4];
  const float* Wr   = (const float*)d_in[5];
  const float* br   = (const float*)d_in[6];
  const float* We   = (const float*)d_in[7];
  const float* att  = (const float*)d_in[8];
  const float* cb   = (const float*)d_in[9];
  const float* gam  = (const float*)d_in[10];
  const float* bet  = (const float*)d_in[11];
  const float* W1   = (const float*)d_in[12];
  const float* b1   = (const float*)d_in[13];
  const float* W2   = (const float*)d_in[14];
  const float* b2   = (const float*)d_in[15];

  char* ws = (char*)d_ws;
  size_t off = 0;
  auto alloc = [&](size_t bytes) {
    void* p = ws + off;
    off = (off + bytes + 255) & ~(size_t)255;
    return p;
  };
  int* rowptr  = (int*)alloc((size_t)N_LAYERS * (N_NODES + 1) * 4);
  int* fillptr = (int*)alloc((size_t)N_LAYERS * N_NODES * 4);
  int2* ep     = (int2*)alloc((size_t)N_LAYERS * N_EDGES * 8);
  float* out_pre = (float*)alloc((size_t)N_LAYERS * N_NODES * 32 * 4);
  float* gsum   = (float*)alloc(N_LAYERS * 32 * 4);
  float* gsumsq = (float*)alloc(N_LAYERS * 32 * 4);
  float* xl     = (float*)alloc((size_t)N_LAYERS * N_NODES * 64 * 4);  // 128 MB
  __hip_bfloat16* w1t = (__hip_bfloat16*)alloc((size_t)896 * 800 * 2);
  __hip_bfloat16* hn  = (__hip_bfloat16*)xl;       // alias: xl dead after attn
  __hip_bfloat16* h1b = (__hip_bfloat16*)out_pre;  // alias: out_pre dead after norm

  hipMemsetAsync(rowptr, 0, (size_t)N_LAYERS * (N_NODES + 1) * 4, stream);
  hipMemsetAsync(gsum, 0, N_LAYERS * 32 * 4, stream);
  hipMemsetAsync(gsumsq, 0, N_LAYERS * 32 * 4, stream);

  int ecnt = N_LAYERS * N_EDGES;
  count_kernel<<<(ecnt + 255) / 256, 256, 0, stream>>>(ei, rowptr);
  scan_kernel<<<N_LAYERS, 1024, 0, stream>>>(rowptr, fillptr);
  fill_kernel<<<(ecnt + 255) / 256, 256, 0, stream>>>(ei, ew, fillptr, ep);
  xl_kernel<<<(N_LAYERS * N_NODES) / 4, 256, 0, stream>>>(x, Wl, bl, xl);
  attn_kernel<<<(N_LAYERS * N_NODES) / 4, 256, 0, stream>>>(
      x, xl, rowptr, ep, Wr, br, We, att, cb, out_pre, gsum, gsumsq);
  norm_kernel<<<(N_LAYERS * N_NODES * 32) / 256, 256, 0, stream>>>(
      out_pre, gsum, gsumsq, gam, bet, hn);
  w1t_kernel<<<dim3(28, 25), dim3(32, 8), 0, stream>>>(W1, w1t);
  gemm1_kernel<<<dim3(7, 157), 256, 0, stream>>>(
      (const short*)hn, (const short*)w1t, b1, h1b);
  gemm2_kernel<<<5000, 256, 0, stream>>>(h1b, W2, b2, (float*)d_out);
}

// Round 5
// 839.023 us; speedup vs baseline: 1.5262x; 1.5262x over previous
//
#include <hip/hip_runtime.h>
#include <hip/hip_bf16.h>

#define N_NODES 20000
#define N_EDGES 100000
#define N_LAYERS 25
#define NPAD 20096   // 157*128
#define EPS_BN 1e-5f
#define LOG2E 1.44269504088896340736f

typedef short short8 __attribute__((ext_vector_type(8)));
typedef short short4v __attribute__((ext_vector_type(4)));
typedef float floatx4 __attribute__((ext_vector_type(4)));

template <int PAT>
__device__ __forceinline__ float swz(float v) {
  return __int_as_float(__builtin_amdgcn_ds_swizzle(__float_as_int(v), PAT));
}

// attention edge weight: leaky-relu, per-head (32-lane) dot with att, exp2
__device__ __forceinline__ float edge_w(float xlv, float w, float wev, float xrn,
                                        float att2v) {
  float v = xlv + fmaf(w, wev, xrn);
  float lk = fmaxf(v, 0.2f * v);
  float p = lk * att2v;
  p += swz<0x041F>(p);
  p += swz<0x081F>(p);
  p += swz<0x101F>(p);
  p += swz<0x201F>(p);
  p += swz<0x401F>(p);
  return __builtin_amdgcn_exp2f(p);  // softmax shift-invariant; logits small
}

// ---------------- CSR build ----------------
__global__ __launch_bounds__(256) void count_kernel(const int* __restrict__ ei,
                                                    int* __restrict__ cnt) {
  int idx = blockIdx.x * 256 + threadIdx.x;
  if (idx >= N_LAYERS * N_EDGES) return;
  int l = idx / N_EDGES, e = idx - l * N_EDGES;
  int dst = ei[(size_t)l * 2 * N_EDGES + N_EDGES + e];
  atomicAdd(&cnt[l * (N_NODES + 1) + dst], 1);
}

__global__ __launch_bounds__(1024) void scan_kernel(int* __restrict__ rowptr,
                                                    int* __restrict__ fillptr) {
  int l = blockIdx.x, t = threadIdx.x;
  int lane = t & 63, wv = t >> 6;  // 16 waves
  __shared__ int wsum[16];
  __shared__ int carry_s;
  if (t == 0) carry_s = 0;
  __syncthreads();
  int base = l * (N_NODES + 1);
  for (int c0 = 0; c0 < N_NODES; c0 += 1024) {
    int i = c0 + t;
    int v = (i < N_NODES) ? rowptr[base + i] : 0;
    int sc = v;
#pragma unroll
    for (int off = 1; off < 64; off <<= 1) {
      int u = __shfl_up(sc, off);
      if (lane >= off) sc += u;
    }
    if (lane == 63) wsum[wv] = sc;
    __syncthreads();
    if (wv == 0) {
      int xx = (lane < 16) ? wsum[lane] : 0;
#pragma unroll
      for (int off = 1; off < 16; off <<= 1) {
        int u = __shfl_up(xx, off);
        if (lane >= off) xx += u;
      }
      if (lane < 16) wsum[lane] = xx;
    }
    __syncthreads();
    int boff = carry_s + (wv > 0 ? wsum[wv - 1] : 0);
    int excl = boff + sc - v;
    if (i < N_NODES) { rowptr[base + i] = excl; fillptr[l * N_NODES + i] = excl; }
    int tot = wsum[15];
    __syncthreads();
    if (t == 0) carry_s += tot;
    __syncthreads();
  }
  if (t == 0) rowptr[base + N_NODES] = carry_s;
}

__global__ __launch_bounds__(256) void fill_kernel(const int* __restrict__ ei,
                                                   const float* __restrict__ ew,
                                                   int* __restrict__ fillptr,
                                                   int2* __restrict__ ep) {
  int idx = blockIdx.x * 256 + threadIdx.x;
  if (idx >= N_LAYERS * N_EDGES) return;
  int l = idx / N_EDGES, e = idx - l * N_EDGES;
  int src = ei[(size_t)l * 2 * N_EDGES + e];
  int dst = ei[(size_t)l * 2 * N_EDGES + N_EDGES + e];
  int pos = atomicAdd(&fillptr[l * N_NODES + dst], 1);
  int2 rec;
  rec.x = src;
  rec.y = __float_as_int(ew[(size_t)l * N_EDGES + e]);
  ep[(size_t)l * N_EDGES + pos] = rec;
}

// ---------------- precompute xl = x @ Wl + bl, [L][N][64] ----------------
__global__ __launch_bounds__(256) void xl_kernel(const float* __restrict__ x,
                                                 const float* __restrict__ Wl,
                                                 const float* __restrict__ bl,
                                                 float* __restrict__ xl) {
  int wid = blockIdx.x * 4 + (threadIdx.x >> 6);
  int lane = threadIdx.x & 63;
  int l = wid / N_NODES, n = wid - l * N_NODES;
  float acc = bl[l * 64 + lane];
#pragma unroll
  for (int k = 0; k < 5; k++)
    acc = fmaf(x[n * 5 + k], Wl[(l * 5 + k) * 64 + lane], acc);
  xl[(size_t)wid * 64 + lane] = acc;
}

// ---------------- fused GAT layer (1 wave per (layer,node)) ----------------
__global__ __launch_bounds__(256) void attn_kernel(
    const float* __restrict__ x, const float* __restrict__ xl,
    const int* __restrict__ rowptr, const int2* __restrict__ ep,
    const float* __restrict__ Wr, const float* __restrict__ br,
    const float* __restrict__ We, const float* __restrict__ att,
    const float* __restrict__ cbias, float* __restrict__ out_pre) {
  int wid = blockIdx.x * 4 + (threadIdx.x >> 6);
  int lane = threadIdx.x & 63;
  int l = wid / N_NODES, n = wid - l * N_NODES;

  const float* xlb = xl + (size_t)l * N_NODES * 64;
  float wev = We[l * 64 + lane];
  float att2v = att[l * 64 + lane] * LOG2E;

  // own-node: xr (recomputed) and xl (from precompute)
  float xrn = br[l * 64 + lane];
#pragma unroll
  for (int k = 0; k < 5; k++)
    xrn = fmaf(x[n * 5 + k], Wr[(l * 5 + k) * 64 + lane], xrn);
  float xln = xlb[n * 64 + lane];

  int start = __builtin_amdgcn_readfirstlane(rowptr[l * (N_NODES + 1) + n]);
  int end   = __builtin_amdgcn_readfirstlane(rowptr[l * (N_NODES + 1) + n + 1]);
  int cnt = end - start;
  int cnt64 = cnt < 64 ? cnt : 64;

  // batch-load up to 64 edge records: lane e holds ep[start+e]; others 0
  int rsrc = 0, rw = 0;
  if (lane < cnt64) {
    int2 rec = ep[(size_t)l * N_EDGES + start + lane];
    rsrc = rec.x;
    rw = rec.y;
  }

  float ssum = 0.f, acc = 0.f, ewsum = 0.f;

  // 1-deep prefetch; (e+1)&63 always indexes a lane holding a valid row id
  int s0 = __builtin_amdgcn_readlane(rsrc, 0);
  float xv = xlb[s0 * 64 + lane];
  for (int e = 0; e < cnt64; e++) {
    int sn = __builtin_amdgcn_readlane(rsrc, (e + 1) & 63);
    float xnext = xlb[sn * 64 + lane];
    float w = __int_as_float(__builtin_amdgcn_readlane(rw, e));
    float pe = edge_w(xv, w, wev, xrn, att2v);
    ssum += pe;
    acc = fmaf(xv, pe, acc);
    ewsum += w;
    xv = xnext;
  }
  // rare overflow path: in-degree > 64
  for (int e = start + 64; e < end; e++) {
    int2 rec = ep[(size_t)l * N_EDGES + e];
    int s = __builtin_amdgcn_readfirstlane(rec.x);
    float w = __int_as_float(__builtin_amdgcn_readfirstlane(rec.y));
    float xg = xlb[s * 64 + lane];
    float pe = edge_w(xg, w, wev, xrn, att2v);
    ssum += pe;
    acc = fmaf(xg, pe, acc);
    ewsum += w;
  }
  // self loop: attr = mean of incoming edge attrs
  {
    float w = ewsum * __builtin_amdgcn_rcpf(fmaxf((float)cnt, 1.f));
    float pe = edge_w(xln, w, wev, xrn, att2v);
    ssum += pe;
    acc = fmaf(xln, pe, acc);
  }
  float outv = acc * __builtin_amdgcn_rcpf(ssum * (float)(cnt + 1));
  float o2 = outv + __shfl_xor(outv, 32);
  if (lane < 32)
    out_pre[((size_t)l * N_NODES + n) * 32 + lane] = 0.5f * o2 + cbias[l * 32 + lane];
}

// ---------------- BatchNorm stats (separate: few blocks -> few atomics) ------
__global__ __launch_bounds__(256) void stats_kernel(const float* __restrict__ out_pre,
                                                    float* __restrict__ gsum,
                                                    float* __restrict__ gsumsq) {
  int l = blockIdx.x >> 4, chunk = blockIdx.x & 15;
  int t = threadIdx.x;
  int c = t & 31, nsub = t >> 5;
  int n0 = chunk * 1250;
  float s1 = 0.f, s2 = 0.f;
  for (int n = n0 + nsub; n < n0 + 1250; n += 8) {
    float v = out_pre[((size_t)l * N_NODES + n) * 32 + c];
    s1 += v; s2 += v * v;
  }
  __shared__ float l1[256], l2[256];
  l1[t] = s1; l2[t] = s2;
  __syncthreads();
  for (int off = 128; off >= 32; off >>= 1) {
    if (t < off) { l1[t] += l1[t + off]; l2[t] += l2[t + off]; }
    __syncthreads();
  }
  if (t < 32) {
    atomicAdd(&gsum[l * 32 + t], l1[t]);
    atomicAdd(&gsumsq[l * 32 + t], l2[t]);
  }
}

// ---------------- normalize + leaky relu -> bf16 [L][NPAD][32] ----------------
// 4 channels/thread: float4 in, 8B bf16 out
__global__ __launch_bounds__(256) void norm_kernel(const float* __restrict__ out_pre,
                                                   const float* __restrict__ gsum,
                                                   const float* __restrict__ gsumsq,
                                                   const float* __restrict__ gamma,
                                                   const float* __restrict__ beta,
                                                   __hip_bfloat16* __restrict__ hn) {
  int idx = blockIdx.x * 256 + threadIdx.x;  // < 25*20000*8
  int l = idx / (N_NODES * 8);
  int rem = idx - l * (N_NODES * 8);
  int n = rem >> 3, q = rem & 7;
  int c0 = q * 4;
  float4 v4 = *(const float4*)(out_pre + ((size_t)l * N_NODES + n) * 32 + c0);
  short4v o;
  float vv[4] = {v4.x, v4.y, v4.z, v4.w};
#pragma unroll
  for (int i = 0; i < 4; i++) {
    int c = c0 + i;
    float mu = gsum[l * 32 + c] * (1.f / N_NODES);
    float var = gsumsq[l * 32 + c] * (1.f / N_NODES) - mu * mu;
    float v = gamma[l * 32 + c] * (vv[i] - mu) * rsqrtf(var + EPS_BN) + beta[l * 32 + c];
    v = v > 0.f ? v : 0.01f * v;
    o[i] = (short)__builtin_bit_cast(unsigned short, (__hip_bfloat16)v);
  }
  *(short4v*)(hn + ((size_t)l * NPAD + n) * 32 + c0) = o;
}

// ---------------- W1 -> bf16 transposed [896][800] ----------------
__global__ void w1t_kernel(const float* __restrict__ W1, __hip_bfloat16* __restrict__ W1bT) {
  __shared__ float tile[32][33];
  int j0 = blockIdx.x * 32, k0 = blockIdx.y * 32;
  int tx = threadIdx.x, ty = threadIdx.y;  // (32,8)
#pragma unroll
  for (int i = 0; i < 4; i++) {
    int k = k0 + ty + i * 8, j = j0 + tx;
    tile[ty + i * 8][tx] = (j < 800) ? W1[k * 800 + j] : 0.f;
  }
  __syncthreads();
#pragma unroll
  for (int i = 0; i < 4; i++) {
    int j = j0 + ty + i * 8, k = k0 + tx;
    W1bT[(size_t)j * 800 + k] = (__hip_bfloat16)tile[tx][ty + i * 8];
  }
}

// ---------------- GEMM1: h[NPAD x 800] @ W1 -> relu -> bf16 h1 ----------------
__global__ __launch_bounds__(256) void gemm1_kernel(const short* __restrict__ hn,
                                                    const short* __restrict__ W1bT,
                                                    const float* __restrict__ b1,
                                                    __hip_bfloat16* __restrict__ h1b) {
  __shared__ __align__(16) short As[128 * 40];
  __shared__ __align__(16) short Bs[128 * 40];
  int t = threadIdx.x;
  int n0 = blockIdx.x * 128, m0 = blockIdx.y * 128;
  int wave = t >> 6, lane = t & 63;
  int wr = wave >> 1, wc = wave & 1;
  int mrow = lane & 15, quad = lane >> 4;
  floatx4 acc[4][4];
#pragma unroll
  for (int i = 0; i < 4; i++)
#pragma unroll
    for (int j = 0; j < 4; j++) acc[i][j] = (floatx4){0.f, 0.f, 0.f, 0.f};

  for (int kt = 0; kt < 25; kt++) {
#pragma unroll
    for (int i = 0; i < 2; i++) {
      int q = t + i * 256;
      int r = q >> 2, sub = q & 3;
      const int4* gA = (const int4*)(hn + ((size_t)kt * NPAD + m0 + r) * 32 + sub * 8);
      *(int4*)(&As[r * 40 + sub * 8]) = *gA;
      const int4* gB = (const int4*)(W1bT + (size_t)(n0 + r) * 800 + kt * 32 + sub * 8);
      *(int4*)(&Bs[r * 40 + sub * 8]) = *gB;
    }
    __syncthreads();
    short8 af[4], bfr[4];
#pragma unroll
    for (int i = 0; i < 4; i++)
      af[i] = *(const short8*)(&As[(wr * 64 + i * 16 + mrow) * 40 + quad * 8]);
#pragma unroll
    for (int j = 0; j < 4; j++)
      bfr[j] = *(const short8*)(&Bs[(wc * 64 + j * 16 + mrow) * 40 + quad * 8]);
#pragma unroll
    for (int i = 0; i < 4; i++)
#pragma unroll
      for (int j = 0; j < 4; j++)
        acc[i][j] = __builtin_amdgcn_mfma_f32_16x16x32_bf16(af[i], bfr[j], acc[i][j], 0, 0, 0);
    __syncthreads();
  }

#pragma unroll
  for (int i = 0; i < 4; i++) {
#pragma unroll
    for (int j = 0; j < 4; j++) {
#pragma unroll
      for (int r = 0; r < 4; r++) {
        int row = m0 + wr * 64 + i * 16 + quad * 4 + r;
        int col = n0 + wc * 64 + j * 16 + mrow;
        if (col < 800) {
          float v = acc[i][j][r] + b1[col];
          v = fmaxf(v, 0.f);
          h1b[(size_t)row * 800 + col] = (__hip_bfloat16)v;
        }
      }
    }
  }
}

// ---------------- GEMM2: h1[20000 x 800] @ W2[800 x 5] + b2 ----------------
__global__ __launch_bounds__(256) void gemm2_kernel(const __hip_bfloat16* __restrict__ h1b,
                                                    const float* __restrict__ W2,
                                                    const float* __restrict__ b2,
                                                    float* __restrict__ out) {
  int wid = blockIdx.x * 4 + (threadIdx.x >> 6);
  int lane = threadIdx.x & 63;
  if (wid >= N_NODES) return;
  const __hip_bfloat16* row = h1b + (size_t)wid * 800;
  float a[5] = {0.f, 0.f, 0.f, 0.f, 0.f};
  for (int k = lane * 2; k < 800; k += 128) {
    float a0 = (float)row[k], a1 = (float)row[k + 1];
#pragma unroll
    for (int j = 0; j < 5; j++) a[j] += a0 * W2[k * 5 + j] + a1 * W2[(k + 1) * 5 + j];
  }
#pragma unroll
  for (int j = 0; j < 5; j++) {
    a[j] += __shfl_xor(a[j], 32);
    a[j] += __shfl_xor(a[j], 16);
    a[j] += __shfl_xor(a[j], 8);
    a[j] += __shfl_xor(a[j], 4);
    a[j] += __shfl_xor(a[j], 2);
    a[j] += __shfl_xor(a[j], 1);
  }
  if (lane == 0) {
#pragma unroll
    for (int j = 0; j < 5; j++) out[wid * 5 + j] = a[j] + b2[j];
  }
}

extern "C" void kernel_launch(void* const* d_in, const int* in_sizes, int n_in,
                              void* d_out, int out_size, void* d_ws, size_t ws_size,
                              hipStream_t stream) {
  const float* x    = (const float*)d_in[0];
  const int*   ei   = (const int*)d_in[1];
  const float* ew   = (const float*)d_in[2];
  const float* Wl   = (const float*)d_in[3];
  const float* bl   = (const float*)d_in[4];
  const float* Wr   = (const float*)d_in[5];
  const float* br   = (const float*)d_in[6];
  const float* We   = (const float*)d_in[7];
  const float* att  = (const float*)d_in[8];
  const float* cb   = (const float*)d_in[9];
  const float* gam  = (const float*)d_in[10];
  const float* bet  = (const float*)d_in[11];
  const float* W1   = (const float*)d_in[12];
  const float* b1   = (const float*)d_in[13];
  const float* W2   = (const float*)d_in[14];
  const float* b2   = (const float*)d_in[15];

  char* ws = (char*)d_ws;
  size_t off = 0;
  auto alloc = [&](size_t bytes) {
    void* p = ws + off;
    off = (off + bytes + 255) & ~(size_t)255;
    return p;
  };
  int* rowptr  = (int*)alloc((size_t)N_LAYERS * (N_NODES + 1) * 4);
  int* fillptr = (int*)alloc((size_t)N_LAYERS * N_NODES * 4);
  int2* ep     = (int2*)alloc((size_t)N_LAYERS * N_EDGES * 8);
  float* out_pre = (float*)alloc((size_t)N_LAYERS * N_NODES * 32 * 4);
  float* gsum   = (float*)alloc(N_LAYERS * 32 * 4);
  float* gsumsq = (float*)alloc(N_LAYERS * 32 * 4);
  float* xl     = (float*)alloc((size_t)N_LAYERS * N_NODES * 64 * 4);  // 128 MB
  __hip_bfloat16* w1t = (__hip_bfloat16*)alloc((size_t)896 * 800 * 2);
  __hip_bfloat16* hn  = (__hip_bfloat16*)xl;       // alias: xl dead after attn
  __hip_bfloat16* h1b = (__hip_bfloat16*)out_pre;  // alias: out_pre dead after norm

  hipMemsetAsync(rowptr, 0, (size_t)N_LAYERS * (N_NODES + 1) * 4, stream);
  hipMemsetAsync(gsum, 0, N_LAYERS * 32 * 4, stream);
  hipMemsetAsync(gsumsq, 0, N_LAYERS * 32 * 4, stream);

  int ecnt = N_LAYERS * N_EDGES;
  count_kernel<<<(ecnt + 255) / 256, 256, 0, stream>>>(ei, rowptr);
  scan_kernel<<<N_LAYERS, 1024, 0, stream>>>(rowptr, fillptr);
  fill_kernel<<<(ecnt + 255) / 256, 256, 0, stream>>>(ei, ew, fillptr, ep);
  xl_kernel<<<(N_LAYERS * N_NODES) / 4, 256, 0, stream>>>(x, Wl, bl, xl);
  attn_kernel<<<(N_LAYERS * N_NODES) / 4, 256, 0, stream>>>(
      x, xl, rowptr, ep, Wr, br, We, att, cb, out_pre);
  stats_kernel<<<N_LAYERS * 16, 256, 0, stream>>>(out_pre, gsum, gsumsq);
  norm_kernel<<<(N_LAYERS * N_NODES * 8) / 256, 256, 0, stream>>>(
      out_pre, gsum, gsumsq, gam, bet, hn);
  w1t_kernel<<<dim3(28, 25), dim3(32, 8), 0, stream>>>(W1, w1t);
  gemm1_kernel<<<dim3(7, 157), 256, 0, stream>>>(
      (const short*)hn, (const short*)w1t, b1, h1b);
  gemm2_kernel<<<5000, 256, 0, stream>>>(h1b, W2, b2, (float*)d_out);
}

// Round 6
// 778.697 us; speedup vs baseline: 1.6445x; 1.0775x over previous
//
#include <hip/hip_runtime.h>
#include <hip/hip_bf16.h>

#define N_NODES 20000
#define N_EDGES 100000
#define N_LAYERS 25
#define NPAD 20096   // 157*128
#define EPS_BN 1e-5f
#define LOG2E 1.44269504088896340736f
#define NL_NN (N_LAYERS * N_NODES)          // 500000
#define SCAN_BLKS ((NL_NN + 1023) / 1024)   // 489

typedef short short8 __attribute__((ext_vector_type(8)));
typedef short short4v __attribute__((ext_vector_type(4)));
typedef float floatx4 __attribute__((ext_vector_type(4)));

template <int PAT>
__device__ __forceinline__ float swz(float v) {
  return __int_as_float(__builtin_amdgcn_ds_swizzle(__float_as_int(v), PAT));
}

__device__ __forceinline__ float ldbf(const unsigned short* __restrict__ p, int idx) {
  return __uint_as_float((unsigned)p[idx] << 16);
}

// ---------------- CSR build: count ----------------
__global__ __launch_bounds__(256) void count_kernel(const int* __restrict__ ei,
                                                    int* __restrict__ cnt) {
  int idx = blockIdx.x * 256 + threadIdx.x;
  if (idx >= N_LAYERS * N_EDGES) return;
  int l = idx / N_EDGES, e = idx - l * N_EDGES;
  int dst = ei[(size_t)l * 2 * N_EDGES + N_EDGES + e];
  atomicAdd(&cnt[l * N_NODES + dst], 1);
}

// ---------------- flat decoupled scan over 500K counts ----------------
__global__ __launch_bounds__(1024) void scan_a(const int* __restrict__ cnt,
                                               int* __restrict__ scn,
                                               int* __restrict__ btot) {
  int t = threadIdx.x, b = blockIdx.x;
  int i = b * 1024 + t;
  int lane = t & 63, wv = t >> 6;
  int v = (i < NL_NN) ? cnt[i] : 0;
  int sc = v;
#pragma unroll
  for (int off = 1; off < 64; off <<= 1) {
    int u = __shfl_up(sc, off);
    if (lane >= off) sc += u;
  }
  __shared__ int ws[16];
  if (lane == 63) ws[wv] = sc;
  __syncthreads();
  if (t < 16) {
    int xx = ws[t];
#pragma unroll
    for (int off = 1; off < 16; off <<= 1) {
      int u = __shfl_up(xx, off);
      if (t >= off) xx += u;
    }
    ws[t] = xx;
  }
  __syncthreads();
  int bofs = wv ? ws[wv - 1] : 0;
  if (i < NL_NN) scn[i] = bofs + sc - v;  // exclusive within block
  if (t == 0) btot[b] = ws[15];
}

__global__ __launch_bounds__(512) void scan_b(const int* __restrict__ btot,
                                              int* __restrict__ boff) {
  int t = threadIdx.x;
  int lane = t & 63, wv = t >> 6;
  int v = (t < SCAN_BLKS) ? btot[t] : 0;
  int sc = v;
#pragma unroll
  for (int off = 1; off < 64; off <<= 1) {
    int u = __shfl_up(sc, off);
    if (lane >= off) sc += u;
  }
  __shared__ int ws[8];
  if (lane == 63) ws[wv] = sc;
  __syncthreads();
  if (t < 8) {
    int xx = ws[t];
#pragma unroll
    for (int off = 1; off < 8; off <<= 1) {
      int u = __shfl_up(xx, off);
      if (t >= off) xx += u;
    }
    ws[t] = xx;
  }
  __syncthreads();
  int bofs = wv ? ws[wv - 1] : 0;
  if (t < SCAN_BLKS) boff[t] = bofs + sc - v;
}

__global__ __launch_bounds__(1024) void scan_c(int* __restrict__ scn,
                                               const int* __restrict__ boff,
                                               int* __restrict__ fillptr) {
  int i = blockIdx.x * 1024 + threadIdx.x;
  if (i < NL_NN) {
    int val = scn[i] + boff[blockIdx.x];
    scn[i] = val;       // becomes final rowptr
    fillptr[i] = val;
  }
  if (i == 0) scn[NL_NN] = N_LAYERS * N_EDGES;  // sentinel
}

__global__ __launch_bounds__(256) void fill_kernel(const int* __restrict__ ei,
                                                   const float* __restrict__ ew,
                                                   int* __restrict__ fillptr,
                                                   int2* __restrict__ ep) {
  int idx = blockIdx.x * 256 + threadIdx.x;
  if (idx >= N_LAYERS * N_EDGES) return;
  int l = idx / N_EDGES, e = idx - l * N_EDGES;
  int src = ei[(size_t)l * 2 * N_EDGES + e];
  int dst = ei[(size_t)l * 2 * N_EDGES + N_EDGES + e];
  int pos = atomicAdd(&fillptr[l * N_NODES + dst], 1);  // global position
  int2 rec;
  rec.x = src;
  rec.y = __float_as_int(ew[(size_t)l * N_EDGES + e]);
  ep[pos] = rec;
}

// ---------------- precompute xl = x @ Wl + bl, bf16 [L][N][64] ----------------
__global__ __launch_bounds__(256) void xl_kernel(const float* __restrict__ x,
                                                 const float* __restrict__ Wl,
                                                 const float* __restrict__ bl,
                                                 unsigned short* __restrict__ xlb) {
  int wid = blockIdx.x * 4 + (threadIdx.x >> 6);
  int lane = threadIdx.x & 63;
  int l = wid / N_NODES, n = wid - l * N_NODES;
  float acc = bl[l * 64 + lane];
#pragma unroll
  for (int k = 0; k < 5; k++)
    acc = fmaf(x[n * 5 + k], Wl[(l * 5 + k) * 64 + lane], acc);
  xlb[(size_t)wid * 64 + lane] =
      __builtin_bit_cast(unsigned short, (__hip_bfloat16)acc);
}

// ---------------- fused GAT layer (1 wave per (layer,node), paired edges) ----
__global__ __launch_bounds__(256) void attn_kernel(
    const float* __restrict__ x, const unsigned short* __restrict__ xlg,
    const int* __restrict__ rowptr, const int2* __restrict__ ep,
    const float* __restrict__ Wr, const float* __restrict__ br,
    const float* __restrict__ We, const float* __restrict__ att,
    const float* __restrict__ cbias, float* __restrict__ out_pre) {
  int wid = blockIdx.x * 4 + (threadIdx.x >> 6);
  int lane = threadIdx.x & 63;
  int l = wid / N_NODES, n = wid - l * N_NODES;

  const unsigned short* xlb = xlg + (size_t)l * N_NODES * 64;
  float wev = We[l * 64 + lane];
  float att2v = att[l * 64 + lane] * LOG2E;

  float xrn = br[l * 64 + lane];
#pragma unroll
  for (int k = 0; k < 5; k++)
    xrn = fmaf(x[n * 5 + k], Wr[(l * 5 + k) * 64 + lane], xrn);
  float xln = ldbf(xlb, n * 64 + lane);

  int start = __builtin_amdgcn_readfirstlane(rowptr[l * N_NODES + n]);
  int end   = __builtin_amdgcn_readfirstlane(rowptr[l * N_NODES + n + 1]);
  int cnt = end - start;
  int cnt64 = cnt < 64 ? cnt : 64;

  // batch-load up to 64 edge records: lane e holds ep[start+e]; others 0
  int rsrc = 0, rw = 0;
  if (lane < cnt64) {
    int2 rec = ep[start + lane];
    rsrc = rec.x;
    rw = rec.y;
  }

  // ewsum once per node: inactive lanes hold rw==0 -> 0.0f
  float ewsum = __int_as_float(rw);
  ewsum += swz<0x041F>(ewsum);
  ewsum += swz<0x081F>(ewsum);
  ewsum += swz<0x101F>(ewsum);
  ewsum += swz<0x201F>(ewsum);
  ewsum += swz<0x401F>(ewsum);
  ewsum += __shfl_xor(ewsum, 32);

  float ssum = 0.f, acc = 0.f;

  if (cnt64 > 0) {
    // 2-deep paired prefetch; (e+k)&63 always a lane holding a valid row id
    int sA = __builtin_amdgcn_readlane(rsrc, 0);
    int sB = __builtin_amdgcn_readlane(rsrc, 1 & 63);
    float xa = ldbf(xlb, sA * 64 + lane);
    float xb = ldbf(xlb, sB * 64 + lane);
    for (int e = 0; e < cnt64; e += 2) {
      int sC = __builtin_amdgcn_readlane(rsrc, (e + 2) & 63);
      int sD = __builtin_amdgcn_readlane(rsrc, (e + 3) & 63);
      float xc = ldbf(xlb, sC * 64 + lane);
      float xd = ldbf(xlb, sD * 64 + lane);
      float w0 = __int_as_float(__builtin_amdgcn_readlane(rw, e));
      float w1 = __int_as_float(__builtin_amdgcn_readlane(rw, (e + 1) & 63));
      // two independent swizzle/exp chains, interleaved for ILP
      float v0 = xa + fmaf(w0, wev, xrn);
      float v1 = xb + fmaf(w1, wev, xrn);
      float lk0 = fmaxf(v0, 0.2f * v0);
      float lk1 = fmaxf(v1, 0.2f * v1);
      float p0 = lk0 * att2v;
      float p1 = lk1 * att2v;
      p0 += swz<0x041F>(p0); p1 += swz<0x041F>(p1);
      p0 += swz<0x081F>(p0); p1 += swz<0x081F>(p1);
      p0 += swz<0x101F>(p0); p1 += swz<0x101F>(p1);
      p0 += swz<0x201F>(p0); p1 += swz<0x201F>(p1);
      p0 += swz<0x401F>(p0); p1 += swz<0x401F>(p1);
      float pe0 = __builtin_amdgcn_exp2f(p0);
      float pe1 = __builtin_amdgcn_exp2f(p1);
      ssum += pe0;
      acc = fmaf(xa, pe0, acc);
      if (e + 1 < cnt64) {  // uniform branch
        ssum += pe1;
        acc = fmaf(xb, pe1, acc);
      }
      xa = xc;
      xb = xd;
    }
  }
  // rare overflow path: in-degree > 64
  for (int e = start + 64; e < end; e++) {
    int2 rec = ep[e];
    int s = __builtin_amdgcn_readfirstlane(rec.x);
    float w = __int_as_float(__builtin_amdgcn_readfirstlane(rec.y));
    float xg = ldbf(xlb, s * 64 + lane);
    float v = xg + fmaf(w, wev, xrn);
    float lk = fmaxf(v, 0.2f * v);
    float p = lk * att2v;
    p += swz<0x041F>(p);
    p += swz<0x081F>(p);
    p += swz<0x101F>(p);
    p += swz<0x201F>(p);
    p += swz<0x401F>(p);
    float pe = __builtin_amdgcn_exp2f(p);
    ssum += pe;
    acc = fmaf(xg, pe, acc);
    ewsum += w;
  }
  // self loop: attr = mean of incoming edge attrs
  {
    float w = ewsum * __builtin_amdgcn_rcpf(fmaxf((float)cnt, 1.f));
    float v = xln + fmaf(w, wev, xrn);
    float lk = fmaxf(v, 0.2f * v);
    float p = lk * att2v;
    p += swz<0x041F>(p);
    p += swz<0x081F>(p);
    p += swz<0x101F>(p);
    p += swz<0x201F>(p);
    p += swz<0x401F>(p);
    float pe = __builtin_amdgcn_exp2f(p);
    ssum += pe;
    acc = fmaf(xln, pe, acc);
  }
  float outv = acc * __builtin_amdgcn_rcpf(ssum * (float)(cnt + 1));
  float o2 = outv + __shfl_xor(outv, 32);
  if (lane < 32)
    out_pre[((size_t)l * N_NODES + n) * 32 + lane] = 0.5f * o2 + cbias[l * 32 + lane];
}

// ---------------- BatchNorm stats (separate: few blocks -> few atomics) ------
__global__ __launch_bounds__(256) void stats_kernel(const float* __restrict__ out_pre,
                                                    float* __restrict__ gsum,
                                                    float* __restrict__ gsumsq) {
  int l = blockIdx.x >> 4, chunk = blockIdx.x & 15;
  int t = threadIdx.x;
  int c = t & 31, nsub = t >> 5;
  int n0 = chunk * 1250;
  float s1 = 0.f, s2 = 0.f;
  for (int n = n0 + nsub; n < n0 + 1250; n += 8) {
    float v = out_pre[((size_t)l * N_NODES + n) * 32 + c];
    s1 += v; s2 += v * v;
  }
  __shared__ float l1[256], l2[256];
  l1[t] = s1; l2[t] = s2;
  __syncthreads();
  for (int off = 128; off >= 32; off >>= 1) {
    if (t < off) { l1[t] += l1[t + off]; l2[t] += l2[t + off]; }
    __syncthreads();
  }
  if (t < 32) {
    atomicAdd(&gsum[l * 32 + t], l1[t]);
    atomicAdd(&gsumsq[l * 32 + t], l2[t]);
  }
}

// ---------------- normalize + leaky relu -> bf16 [L][NPAD][32] ----------------
__global__ __launch_bounds__(256) void norm_kernel(const float* __restrict__ out_pre,
                                                   const float* __restrict__ gsum,
                                                   const float* __restrict__ gsumsq,
                                                   const float* __restrict__ gamma,
                                                   const float* __restrict__ beta,
                                                   __hip_bfloat16* __restrict__ hn) {
  int idx = blockIdx.x * 256 + threadIdx.x;  // < 25*20000*8
  int l = idx / (N_NODES * 8);
  int rem = idx - l * (N_NODES * 8);
  int n = rem >> 3, q = rem & 7;
  int c0 = q * 4;
  float4 v4 = *(const float4*)(out_pre + ((size_t)l * N_NODES + n) * 32 + c0);
  short4v o;
  float vv[4] = {v4.x, v4.y, v4.z, v4.w};
#pragma unroll
  for (int i = 0; i < 4; i++) {
    int c = c0 + i;
    float mu = gsum[l * 32 + c] * (1.f / N_NODES);
    float var = gsumsq[l * 32 + c] * (1.f / N_NODES) - mu * mu;
    float v = gamma[l * 32 + c] * (vv[i] - mu) * rsqrtf(var + EPS_BN) + beta[l * 32 + c];
    v = v > 0.f ? v : 0.01f * v;
    o[i] = (short)__builtin_bit_cast(unsigned short, (__hip_bfloat16)v);
  }
  *(short4v*)(hn + ((size_t)l * NPAD + n) * 32 + c0) = o;
}

// ---------------- W1 -> bf16 transposed [896][800] ----------------
__global__ void w1t_kernel(const float* __restrict__ W1, __hip_bfloat16* __restrict__ W1bT) {
  __shared__ float tile[32][33];
  int j0 = blockIdx.x * 32, k0 = blockIdx.y * 32;
  int tx = threadIdx.x, ty = threadIdx.y;  // (32,8)
#pragma unroll
  for (int i = 0; i < 4; i++) {
    int k = k0 + ty + i * 8, j = j0 + tx;
    tile[ty + i * 8][tx] = (j < 800) ? W1[k * 800 + j] : 0.f;
  }
  __syncthreads();
#pragma unroll
  for (int i = 0; i < 4; i++) {
    int j = j0 + ty + i * 8, k = k0 + tx;
    W1bT[(size_t)j * 800 + k] = (__hip_bfloat16)tile[tx][ty + i * 8];
  }
}

// ---------------- GEMM1: h[NPAD x 800] @ W1 -> relu -> bf16 h1 ----------------
__global__ __launch_bounds__(256) void gemm1_kernel(const short* __restrict__ hn,
                                                    const short* __restrict__ W1bT,
                                                    const float* __restrict__ b1,
                                                    __hip_bfloat16* __restrict__ h1b) {
  __shared__ __align__(16) short As[128 * 40];
  __shared__ __align__(16) short Bs[128 * 40];
  int t = threadIdx.x;
  int n0 = blockIdx.x * 128, m0 = blockIdx.y * 128;
  int wave = t >> 6, lane = t & 63;
  int wr = wave >> 1, wc = wave & 1;
  int mrow = lane & 15, quad = lane >> 4;
  floatx4 acc[4][4];
#pragma unroll
  for (int i = 0; i < 4; i++)
#pragma unroll
    for (int j = 0; j < 4; j++) acc[i][j] = (floatx4){0.f, 0.f, 0.f, 0.f};

  for (int kt = 0; kt < 25; kt++) {
#pragma unroll
    for (int i = 0; i < 2; i++) {
      int q = t + i * 256;
      int r = q >> 2, sub = q & 3;
      const int4* gA = (const int4*)(hn + ((size_t)kt * NPAD + m0 + r) * 32 + sub * 8);
      *(int4*)(&As[r * 40 + sub * 8]) = *gA;
      const int4* gB = (const int4*)(W1bT + (size_t)(n0 + r) * 800 + kt * 32 + sub * 8);
      *(int4*)(&Bs[r * 40 + sub * 8]) = *gB;
    }
    __syncthreads();
    short8 af[4], bfr[4];
#pragma unroll
    for (int i = 0; i < 4; i++)
      af[i] = *(const short8*)(&As[(wr * 64 + i * 16 + mrow) * 40 + quad * 8]);
#pragma unroll
    for (int j = 0; j < 4; j++)
      bfr[j] = *(const short8*)(&Bs[(wc * 64 + j * 16 + mrow) * 40 + quad * 8]);
#pragma unroll
    for (int i = 0; i < 4; i++)
#pragma unroll
      for (int j = 0; j < 4; j++)
        acc[i][j] = __builtin_amdgcn_mfma_f32_16x16x32_bf16(af[i], bfr[j], acc[i][j], 0, 0, 0);
    __syncthreads();
  }

#pragma unroll
  for (int i = 0; i < 4; i++) {
#pragma unroll
    for (int j = 0; j < 4; j++) {
#pragma unroll
      for (int r = 0; r < 4; r++) {
        int row = m0 + wr * 64 + i * 16 + quad * 4 + r;
        int col = n0 + wc * 64 + j * 16 + mrow;
        if (col < 800) {
          float v = acc[i][j][r] + b1[col];
          v = fmaxf(v, 0.f);
          h1b[(size_t)row * 800 + col] = (__hip_bfloat16)v;
        }
      }
    }
  }
}

// ---------------- GEMM2: h1[20000 x 800] @ W2[800 x 5] + b2 ----------------
__global__ __launch_bounds__(256) void gemm2_kernel(const __hip_bfloat16* __restrict__ h1b,
                                                    const float* __restrict__ W2,
                                                    const float* __restrict__ b2,
                                                    float* __restrict__ out) {
  int wid = blockIdx.x * 4 + (threadIdx.x >> 6);
  int lane = threadIdx.x & 63;
  if (wid >= N_NODES) return;
  const __hip_bfloat16* row = h1b + (size_t)wid * 800;
  float a[5] = {0.f, 0.f, 0.f, 0.f, 0.f};
  for (int k = lane * 2; k < 800; k += 128) {
    float a0 = (float)row[k], a1 = (float)row[k + 1];
#pragma unroll
    for (int j = 0; j < 5; j++) a[j] += a0 * W2[k * 5 + j] + a1 * W2[(k + 1) * 5 + j];
  }
#pragma unroll
  for (int j = 0; j < 5; j++) {
    a[j] += __shfl_xor(a[j], 32);
    a[j] += __shfl_xor(a[j], 16);
    a[j] += __shfl_xor(a[j], 8);
    a[j] += __shfl_xor(a[j], 4);
    a[j] += __shfl_xor(a[j], 2);
    a[j] += __shfl_xor(a[j], 1);
  }
  if (lane == 0) {
#pragma unroll
    for (int j = 0; j < 5; j++) out[wid * 5 + j] = a[j] + b2[j];
  }
}

extern "C" void kernel_launch(void* const* d_in, const int* in_sizes, int n_in,
                              void* d_out, int out_size, void* d_ws, size_t ws_size,
                              hipStream_t stream) {
  const float* x    = (const float*)d_in[0];
  const int*   ei   = (const int*)d_in[1];
  const float* ew   = (const float*)d_in[2];
  const float* Wl   = (const float*)d_in[3];
  const float* bl   = (const float*)d_in[4];
  const float* Wr   = (const float*)d_in[5];
  const float* br   = (const float*)d_in[6];
  const float* We   = (const float*)d_in[7];
  const float* att  = (const float*)d_in[8];
  const float* cb   = (const float*)d_in[9];
  const float* gam  = (const float*)d_in[10];
  const float* bet  = (const float*)d_in[11];
  const float* W1   = (const float*)d_in[12];
  const float* b1   = (const float*)d_in[13];
  const float* W2   = (const float*)d_in[14];
  const float* b2   = (const float*)d_in[15];

  char* ws = (char*)d_ws;
  size_t off = 0;
  auto alloc = [&](size_t bytes) {
    void* p = ws + off;
    off = (off + bytes + 255) & ~(size_t)255;
    return p;
  };
  int* cnt     = (int*)alloc((size_t)NL_NN * 4);
  int* rowptr  = (int*)alloc((size_t)(NL_NN + 1) * 4);  // scan_a scn -> scan_c final
  int* btot    = (int*)alloc(SCAN_BLKS * 4);
  int* boff    = (int*)alloc(SCAN_BLKS * 4);
  int* fillptr = (int*)alloc((size_t)NL_NN * 4);
  int2* ep     = (int2*)alloc((size_t)N_LAYERS * N_EDGES * 8);
  float* out_pre = (float*)alloc((size_t)N_LAYERS * N_NODES * 32 * 4);
  float* gsum   = (float*)alloc(N_LAYERS * 32 * 4);
  float* gsumsq = (float*)alloc(N_LAYERS * 32 * 4);
  unsigned short* xlb = (unsigned short*)alloc((size_t)N_LAYERS * N_NODES * 64 * 2);  // 64 MB
  __hip_bfloat16* w1t = (__hip_bfloat16*)alloc((size_t)896 * 800 * 2);
  __hip_bfloat16* hn  = (__hip_bfloat16*)xlb;      // alias: xlb dead after attn
  __hip_bfloat16* h1b = (__hip_bfloat16*)out_pre;  // alias: out_pre dead after norm

  hipMemsetAsync(cnt, 0, (size_t)NL_NN * 4, stream);
  hipMemsetAsync(gsum, 0, N_LAYERS * 32 * 4, stream);
  hipMemsetAsync(gsumsq, 0, N_LAYERS * 32 * 4, stream);

  int ecnt = N_LAYERS * N_EDGES;
  count_kernel<<<(ecnt + 255) / 256, 256, 0, stream>>>(ei, cnt);
  scan_a<<<SCAN_BLKS, 1024, 0, stream>>>(cnt, rowptr, btot);
  scan_b<<<1, 512, 0, stream>>>(btot, boff);
  scan_c<<<SCAN_BLKS, 1024, 0, stream>>>(rowptr, boff, fillptr);
  fill_kernel<<<(ecnt + 255) / 256, 256, 0, stream>>>(ei, ew, fillptr, ep);
  xl_kernel<<<(N_LAYERS * N_NODES) / 4, 256, 0, stream>>>(x, Wl, bl, xlb);
  attn_kernel<<<(N_LAYERS * N_NODES) / 4, 256, 0, stream>>>(
      x, xlb, rowptr, ep, Wr, br, We, att, cb, out_pre);
  stats_kernel<<<N_LAYERS * 16, 256, 0, stream>>>(out_pre, gsum, gsumsq);
  norm_kernel<<<(N_LAYERS * N_NODES * 8) / 256, 256, 0, stream>>>(
      out_pre, gsum, gsumsq, gam, bet, hn);
  w1t_kernel<<<dim3(28, 25), dim3(32, 8), 0, stream>>>(W1, w1t);
  gemm1_kernel<<<dim3(7, 157), 256, 0, stream>>>(
      (const short*)hn, (const short*)w1t, b1, h1b);
  gemm2_kernel<<<5000, 256, 0, stream>>>(h1b, W2, b2, (float*)d_out);
}

// Round 7
// 707.946 us; speedup vs baseline: 1.8088x; 1.0999x over previous
//
#include <hip/hip_runtime.h>
#include <hip/hip_bf16.h>

#define N_NODES 20000
#define N_EDGES 100000
#define N_LAYERS 25
#define NPAD 20096   // 157*128
#define EPS_BN 1e-5f
#define LOG2E 1.44269504088896340736f
#define NL_NN (N_LAYERS * N_NODES)          // 500000
#define SCAN_BLKS ((NL_NN + 1023) / 1024)   // 489
#define HALF_N 10000

typedef short short8 __attribute__((ext_vector_type(8)));
typedef short short4v __attribute__((ext_vector_type(4)));
typedef float floatx4 __attribute__((ext_vector_type(4)));

template <int PAT>
__device__ __forceinline__ float swz(float v) {
  return __int_as_float(__builtin_amdgcn_ds_swizzle(__float_as_int(v), PAT));
}

template <int CTRL>
__device__ __forceinline__ float dpp_add(float v) {
  int r = __builtin_amdgcn_update_dpp(0, __float_as_int(v), CTRL, 0xF, 0xF, true);
  return v + __int_as_float(r);
}

// sum over each 32-lane half (head), broadcast to all lanes of the half.
// xor1/2 = quad_perm, xor4 = row_half_mirror, xor8 = row_mirror (VALU+DPP),
// xor16 = ds_swizzle (only DS op in the chain).
__device__ __forceinline__ float headsum(float p) {
  p = dpp_add<0xB1>(p);    // quad_perm [1,0,3,2]  : xor1
  p = dpp_add<0x4E>(p);    // quad_perm [2,3,0,1]  : xor2
  p = dpp_add<0x141>(p);   // row_half_mirror      : xor4
  p = dpp_add<0x140>(p);   // row_mirror           : xor8
  p += swz<0x401F>(p);     // xor16
  return p;
}

__device__ __forceinline__ float ldbf(const unsigned short* __restrict__ p, int idx) {
  return __uint_as_float((unsigned)p[idx] << 16);
}

// ---------------- CSR count: LDS histogram per (layer, half-range) ----------
__global__ __launch_bounds__(1024) void count_kernel(const int* __restrict__ ei,
                                                     int* __restrict__ cnt) {
  __shared__ int h[HALF_N];  // 40 KB
  int l = blockIdx.x >> 1, half = blockIdx.x & 1;
  int base = half * HALF_N;
  for (int i = threadIdx.x; i < HALF_N; i += 1024) h[i] = 0;
  __syncthreads();
  const int* dstp = ei + (size_t)l * 2 * N_EDGES + N_EDGES;
  for (int e = threadIdx.x; e < N_EDGES; e += 1024) {
    int d = dstp[e] - base;
    if ((unsigned)d < (unsigned)HALF_N) atomicAdd(&h[d], 1);
  }
  __syncthreads();
  int* outp = cnt + l * N_NODES + base;
  for (int i = threadIdx.x; i < HALF_N; i += 1024) outp[i] = h[i];
}

// ---------------- flat decoupled scan over 500K counts ----------------
__global__ __launch_bounds__(1024) void scan_a(const int* __restrict__ cnt,
                                               int* __restrict__ scn,
                                               int* __restrict__ btot) {
  int t = threadIdx.x, b = blockIdx.x;
  int i = b * 1024 + t;
  int lane = t & 63, wv = t >> 6;
  int v = (i < NL_NN) ? cnt[i] : 0;
  int sc = v;
#pragma unroll
  for (int off = 1; off < 64; off <<= 1) {
    int u = __shfl_up(sc, off);
    if (lane >= off) sc += u;
  }
  __shared__ int ws[16];
  if (lane == 63) ws[wv] = sc;
  __syncthreads();
  if (t < 16) {
    int xx = ws[t];
#pragma unroll
    for (int off = 1; off < 16; off <<= 1) {
      int u = __shfl_up(xx, off);
      if (t >= off) xx += u;
    }
    ws[t] = xx;
  }
  __syncthreads();
  int bofs = wv ? ws[wv - 1] : 0;
  if (i < NL_NN) scn[i] = bofs + sc - v;  // exclusive within block
  if (t == 0) btot[b] = ws[15];
}

__global__ __launch_bounds__(512) void scan_b(const int* __restrict__ btot,
                                              int* __restrict__ boff) {
  int t = threadIdx.x;
  int lane = t & 63, wv = t >> 6;
  int v = (t < SCAN_BLKS) ? btot[t] : 0;
  int sc = v;
#pragma unroll
  for (int off = 1; off < 64; off <<= 1) {
    int u = __shfl_up(sc, off);
    if (lane >= off) sc += u;
  }
  __shared__ int ws[8];
  if (lane == 63) ws[wv] = sc;
  __syncthreads();
  if (t < 8) {
    int xx = ws[t];
#pragma unroll
    for (int off = 1; off < 8; off <<= 1) {
      int u = __shfl_up(xx, off);
      if (t >= off) xx += u;
    }
    ws[t] = xx;
  }
  __syncthreads();
  int bofs = wv ? ws[wv - 1] : 0;
  if (t < SCAN_BLKS) boff[t] = bofs + sc - v;
}

__global__ __launch_bounds__(1024) void scan_c(int* __restrict__ scn,
                                               const int* __restrict__ boff) {
  int i = blockIdx.x * 1024 + threadIdx.x;
  if (i < NL_NN) scn[i] += boff[blockIdx.x];  // final rowptr
  if (i == 0) scn[NL_NN] = N_LAYERS * N_EDGES;
}

// ---------------- fill: LDS position counters, no global atomics ------------
__global__ __launch_bounds__(1024) void fill_kernel(const int* __restrict__ ei,
                                                    const float* __restrict__ ew,
                                                    const int* __restrict__ rowptr,
                                                    int2* __restrict__ ep) {
  __shared__ int off[HALF_N];  // 40 KB, holds global positions
  int l = blockIdx.x >> 1, half = blockIdx.x & 1;
  int base = half * HALF_N;
  for (int i = threadIdx.x; i < HALF_N; i += 1024)
    off[i] = rowptr[l * N_NODES + base + i];
  __syncthreads();
  const int* srcp = ei + (size_t)l * 2 * N_EDGES;
  const int* dstp = srcp + N_EDGES;
  const float* ewp = ew + (size_t)l * N_EDGES;
  for (int e = threadIdx.x; e < N_EDGES; e += 1024) {
    int d = dstp[e] - base;
    if ((unsigned)d < (unsigned)HALF_N) {
      int pos = atomicAdd(&off[d], 1);
      int2 rec;
      rec.x = srcp[e];
      rec.y = __float_as_int(ewp[e]);
      ep[pos] = rec;
    }
  }
}

// ---------------- precompute xl,xr = x@W{l,r}+b{l,r}, bf16 [L][N][64] --------
__global__ __launch_bounds__(256) void xlr_kernel(const float* __restrict__ x,
                                                  const float* __restrict__ Wl,
                                                  const float* __restrict__ bl,
                                                  const float* __restrict__ Wr,
                                                  const float* __restrict__ br,
                                                  unsigned short* __restrict__ xlb,
                                                  unsigned short* __restrict__ xrb) {
  int wid = blockIdx.x * 4 + (threadIdx.x >> 6);
  int lane = threadIdx.x & 63;
  int l = wid / N_NODES, n = wid - l * N_NODES;
  float a = bl[l * 64 + lane];
  float b = br[l * 64 + lane];
#pragma unroll
  for (int k = 0; k < 5; k++) {
    float xk = x[n * 5 + k];
    a = fmaf(xk, Wl[(l * 5 + k) * 64 + lane], a);
    b = fmaf(xk, Wr[(l * 5 + k) * 64 + lane], b);
  }
  xlb[(size_t)wid * 64 + lane] = __builtin_bit_cast(unsigned short, (__hip_bfloat16)a);
  xrb[(size_t)wid * 64 + lane] = __builtin_bit_cast(unsigned short, (__hip_bfloat16)b);
}

// ---------------- fused GAT layer (1 wave per (layer,node), paired edges) ----
__global__ __launch_bounds__(256) void attn_kernel(
    const unsigned short* __restrict__ xlg, const unsigned short* __restrict__ xrg,
    const int* __restrict__ rowptr, const int2* __restrict__ ep,
    const float* __restrict__ We, const float* __restrict__ att,
    const float* __restrict__ cbias, float* __restrict__ out_pre) {
  int wid = blockIdx.x * 4 + (threadIdx.x >> 6);
  int lane = threadIdx.x & 63;
  int l = wid / N_NODES, n = wid - l * N_NODES;

  const unsigned short* xlb = xlg + (size_t)l * N_NODES * 64;
  float wev = We[l * 64 + lane];
  float att2v = att[l * 64 + lane] * LOG2E;

  float xrn = ldbf(xrg, (size_t)(l * N_NODES + n) * 64 + lane);
  float xln = ldbf(xlb, n * 64 + lane);

  int start = __builtin_amdgcn_readfirstlane(rowptr[l * N_NODES + n]);
  int end   = __builtin_amdgcn_readfirstlane(rowptr[l * N_NODES + n + 1]);
  int cnt = end - start;
  int cnt64 = cnt < 64 ? cnt : 64;

  // batch-load up to 64 edge records: lane e holds ep[start+e]; others 0
  int rsrc = 0, rw = 0;
  if (lane < cnt64) {
    int2 rec = ep[start + lane];
    rsrc = rec.x;
    rw = rec.y;
  }

  // ewsum once per node (inactive lanes hold 0)
  float ewsum = headsum(__int_as_float(rw));
  ewsum += __shfl_xor(ewsum, 32);

  float ssum = 0.f, acc = 0.f;

  if (cnt64 > 0) {
    int sA = __builtin_amdgcn_readlane(rsrc, 0);
    int sB = __builtin_amdgcn_readlane(rsrc, 1 & 63);
    float xa = ldbf(xlb, sA * 64 + lane);
    float xb = ldbf(xlb, sB * 64 + lane);
    for (int e = 0; e < cnt64; e += 2) {
      int sC = __builtin_amdgcn_readlane(rsrc, (e + 2) & 63);
      int sD = __builtin_amdgcn_readlane(rsrc, (e + 3) & 63);
      float xc = ldbf(xlb, sC * 64 + lane);
      float xd = ldbf(xlb, sD * 64 + lane);
      float w0 = __int_as_float(__builtin_amdgcn_readlane(rw, e));
      float w1 = __int_as_float(__builtin_amdgcn_readlane(rw, (e + 1) & 63));
      float v0 = xa + fmaf(w0, wev, xrn);
      float v1 = xb + fmaf(w1, wev, xrn);
      float lk0 = fmaxf(v0, 0.2f * v0);
      float lk1 = fmaxf(v1, 0.2f * v1);
      float p0 = lk0 * att2v;
      float p1 = lk1 * att2v;
      p0 = dpp_add<0xB1>(p0);  p1 = dpp_add<0xB1>(p1);
      p0 = dpp_add<0x4E>(p0);  p1 = dpp_add<0x4E>(p1);
      p0 = dpp_add<0x141>(p0); p1 = dpp_add<0x141>(p1);
      p0 = dpp_add<0x140>(p0); p1 = dpp_add<0x140>(p1);
      p0 += swz<0x401F>(p0);   p1 += swz<0x401F>(p1);
      float pe0 = __builtin_amdgcn_exp2f(p0);
      float pe1 = __builtin_amdgcn_exp2f(p1);
      ssum += pe0;
      acc = fmaf(xa, pe0, acc);
      if (e + 1 < cnt64) {  // uniform branch
        ssum += pe1;
        acc = fmaf(xb, pe1, acc);
      }
      xa = xc;
      xb = xd;
    }
  }
  // rare overflow path: in-degree > 64
  for (int e = start + 64; e < end; e++) {
    int2 rec = ep[e];
    int s = __builtin_amdgcn_readfirstlane(rec.x);
    float w = __int_as_float(__builtin_amdgcn_readfirstlane(rec.y));
    float xg = ldbf(xlb, s * 64 + lane);
    float v = xg + fmaf(w, wev, xrn);
    float lk = fmaxf(v, 0.2f * v);
    float pe = __builtin_amdgcn_exp2f(headsum(lk * att2v));
    ssum += pe;
    acc = fmaf(xg, pe, acc);
    ewsum += w;
  }
  // self loop: attr = mean of incoming edge attrs
  {
    float w = ewsum * __builtin_amdgcn_rcpf(fmaxf((float)cnt, 1.f));
    float v = xln + fmaf(w, wev, xrn);
    float lk = fmaxf(v, 0.2f * v);
    float pe = __builtin_amdgcn_exp2f(headsum(lk * att2v));
    ssum += pe;
    acc = fmaf(xln, pe, acc);
  }
  float outv = acc * __builtin_amdgcn_rcpf(ssum * (float)(cnt + 1));
  float o2 = outv + __shfl_xor(outv, 32);
  if (lane < 32)
    out_pre[((size_t)l * N_NODES + n) * 32 + lane] = 0.5f * o2 + cbias[l * 32 + lane];
}

// ---------------- BatchNorm stats ----------------
__global__ __launch_bounds__(256) void stats_kernel(const float* __restrict__ out_pre,
                                                    float* __restrict__ gsum,
                                                    float* __restrict__ gsumsq) {
  int l = blockIdx.x >> 4, chunk = blockIdx.x & 15;
  int t = threadIdx.x;
  int c = t & 31, nsub = t >> 5;
  int n0 = chunk * 1250;
  float s1 = 0.f, s2 = 0.f;
  for (int n = n0 + nsub; n < n0 + 1250; n += 8) {
    float v = out_pre[((size_t)l * N_NODES + n) * 32 + c];
    s1 += v; s2 += v * v;
  }
  __shared__ float l1[256], l2[256];
  l1[t] = s1; l2[t] = s2;
  __syncthreads();
  for (int off = 128; off >= 32; off >>= 1) {
    if (t < off) { l1[t] += l1[t + off]; l2[t] += l2[t + off]; }
    __syncthreads();
  }
  if (t < 32) {
    atomicAdd(&gsum[l * 32 + t], l1[t]);
    atomicAdd(&gsumsq[l * 32 + t], l2[t]);
  }
}

// ---------------- normalize + leaky relu -> bf16 [L][NPAD][32] ----------------
__global__ __launch_bounds__(256) void norm_kernel(const float* __restrict__ out_pre,
                                                   const float* __restrict__ gsum,
                                                   const float* __restrict__ gsumsq,
                                                   const float* __restrict__ gamma,
                                                   const float* __restrict__ beta,
                                                   __hip_bfloat16* __restrict__ hn) {
  int idx = blockIdx.x * 256 + threadIdx.x;  // < 25*20000*8
  int l = idx / (N_NODES * 8);
  int rem = idx - l * (N_NODES * 8);
  int n = rem >> 3, q = rem & 7;
  int c0 = q * 4;
  float4 v4 = *(const float4*)(out_pre + ((size_t)l * N_NODES + n) * 32 + c0);
  short4v o;
  float vv[4] = {v4.x, v4.y, v4.z, v4.w};
#pragma unroll
  for (int i = 0; i < 4; i++) {
    int c = c0 + i;
    float mu = gsum[l * 32 + c] * (1.f / N_NODES);
    float var = gsumsq[l * 32 + c] * (1.f / N_NODES) - mu * mu;
    float v = gamma[l * 32 + c] * (vv[i] - mu) * rsqrtf(var + EPS_BN) + beta[l * 32 + c];
    v = v > 0.f ? v : 0.01f * v;
    o[i] = (short)__builtin_bit_cast(unsigned short, (__hip_bfloat16)v);
  }
  *(short4v*)(hn + ((size_t)l * NPAD + n) * 32 + c0) = o;
}

// ---------------- W1 -> bf16 transposed [896][800] ----------------
__global__ void w1t_kernel(const float* __restrict__ W1, __hip_bfloat16* __restrict__ W1bT) {
  __shared__ float tile[32][33];
  int j0 = blockIdx.x * 32, k0 = blockIdx.y * 32;
  int tx = threadIdx.x, ty = threadIdx.y;  // (32,8)
#pragma unroll
  for (int i = 0; i < 4; i++) {
    int k = k0 + ty + i * 8, j = j0 + tx;
    tile[ty + i * 8][tx] = (j < 800) ? W1[k * 800 + j] : 0.f;
  }
  __syncthreads();
#pragma unroll
  for (int i = 0; i < 4; i++) {
    int j = j0 + ty + i * 8, k = k0 + tx;
    W1bT[(size_t)j * 800 + k] = (__hip_bfloat16)tile[tx][ty + i * 8];
  }
}

// ---------------- GEMM1: h[NPAD x 800] @ W1 -> relu -> bf16 h1 ----------------
// register-prefetched k-tiles: next tile's global loads issue after barrier,
// overlap with MFMA of current tile.
__global__ __launch_bounds__(256) void gemm1_kernel(const short* __restrict__ hn,
                                                    const short* __restrict__ W1bT,
                                                    const float* __restrict__ b1,
                                                    __hip_bfloat16* __restrict__ h1b) {
  __shared__ __align__(16) short As[128 * 40];
  __shared__ __align__(16) short Bs[128 * 40];
  int t = threadIdx.x;
  int n0 = blockIdx.x * 128, m0 = blockIdx.y * 128;
  int wave = t >> 6, lane = t & 63;
  int wr = wave >> 1, wc = wave & 1;
  int mrow = lane & 15, quad = lane >> 4;
  floatx4 acc[4][4];
#pragma unroll
  for (int i = 0; i < 4; i++)
#pragma unroll
    for (int j = 0; j < 4; j++) acc[i][j] = (floatx4){0.f, 0.f, 0.f, 0.f};

  int r0 = t >> 2, s0 = t & 3;
  int r1 = (t + 256) >> 2, s1 = (t + 256) & 3;
  const short* aB0 = hn + (size_t)(m0 + r0) * 32 + s0 * 8;
  const short* aB1 = hn + (size_t)(m0 + r1) * 32 + s1 * 8;
  const short* bB0 = W1bT + (size_t)(n0 + r0) * 800 + s0 * 8;
  const short* bB1 = W1bT + (size_t)(n0 + r1) * 800 + s1 * 8;
  const size_t ak = (size_t)NPAD * 32;

  int4 pa0 = *(const int4*)aB0;
  int4 pa1 = *(const int4*)aB1;
  int4 pb0 = *(const int4*)bB0;
  int4 pb1 = *(const int4*)bB1;

  for (int kt = 0; kt < 25; kt++) {
    *(int4*)(&As[r0 * 40 + s0 * 8]) = pa0;
    *(int4*)(&As[r1 * 40 + s1 * 8]) = pa1;
    *(int4*)(&Bs[r0 * 40 + s0 * 8]) = pb0;
    *(int4*)(&Bs[r1 * 40 + s1 * 8]) = pb1;
    __syncthreads();
    int ktn = kt < 24 ? kt + 1 : 24;  // last-iter loads are valid but unused
    pa0 = *(const int4*)(aB0 + (size_t)ktn * ak);
    pa1 = *(const int4*)(aB1 + (size_t)ktn * ak);
    pb0 = *(const int4*)(bB0 + ktn * 32);
    pb1 = *(const int4*)(bB1 + ktn * 32);
    short8 af[4], bfr[4];
#pragma unroll
    for (int i = 0; i < 4; i++)
      af[i] = *(const short8*)(&As[(wr * 64 + i * 16 + mrow) * 40 + quad * 8]);
#pragma unroll
    for (int j = 0; j < 4; j++)
      bfr[j] = *(const short8*)(&Bs[(wc * 64 + j * 16 + mrow) * 40 + quad * 8]);
#pragma unroll
    for (int i = 0; i < 4; i++)
#pragma unroll
      for (int j = 0; j < 4; j++)
        acc[i][j] = __builtin_amdgcn_mfma_f32_16x16x32_bf16(af[i], bfr[j], acc[i][j], 0, 0, 0);
    __syncthreads();
  }

#pragma unroll
  for (int i = 0; i < 4; i++) {
#pragma unroll
    for (int j = 0; j < 4; j++) {
#pragma unroll
      for (int r = 0; r < 4; r++) {
        int row = m0 + wr * 64 + i * 16 + quad * 4 + r;
        int col = n0 + wc * 64 + j * 16 + mrow;
        if (col < 800) {
          float v = acc[i][j][r] + b1[col];
          v = fmaxf(v, 0.f);
          h1b[(size_t)row * 800 + col] = (__hip_bfloat16)v;
        }
      }
    }
  }
}

// ---------------- GEMM2: h1[20000 x 800] @ W2[800 x 5] + b2 ----------------
__global__ __launch_bounds__(256) void gemm2_kernel(const __hip_bfloat16* __restrict__ h1b,
                                                    const float* __restrict__ W2,
                                                    const float* __restrict__ b2,
                                                    float* __restrict__ out) {
  int wid = blockIdx.x * 4 + (threadIdx.x >> 6);
  int lane = threadIdx.x & 63;
  if (wid >= N_NODES) return;
  const __hip_bfloat16* row = h1b + (size_t)wid * 800;
  float a[5] = {0.f, 0.f, 0.f, 0.f, 0.f};
  for (int k = lane * 2; k < 800; k += 128) {
    float a0 = (float)row[k], a1 = (float)row[k + 1];
#pragma unroll
    for (int j = 0; j < 5; j++) a[j] += a0 * W2[k * 5 + j] + a1 * W2[(k + 1) * 5 + j];
  }
#pragma unroll
  for (int j = 0; j < 5; j++) {
    a[j] += __shfl_xor(a[j], 32);
    a[j] += __shfl_xor(a[j], 16);
    a[j] += __shfl_xor(a[j], 8);
    a[j] += __shfl_xor(a[j], 4);
    a[j] += __shfl_xor(a[j], 2);
    a[j] += __shfl_xor(a[j], 1);
  }
  if (lane == 0) {
#pragma unroll
    for (int j = 0; j < 5; j++) out[wid * 5 + j] = a[j] + b2[j];
  }
}

extern "C" void kernel_launch(void* const* d_in, const int* in_sizes, int n_in,
                              void* d_out, int out_size, void* d_ws, size_t ws_size,
                              hipStream_t stream) {
  const float* x    = (const float*)d_in[0];
  const int*   ei   = (const int*)d_in[1];
  const float* ew   = (const float*)d_in[2];
  const float* Wl   = (const float*)d_in[3];
  const float* bl   = (const float*)d_in[4];
  const float* Wr   = (const float*)d_in[5];
  const float* br   = (const float*)d_in[6];
  const float* We   = (const float*)d_in[7];
  const float* att  = (const float*)d_in[8];
  const float* cb   = (const float*)d_in[9];
  const float* gam  = (const float*)d_in[10];
  const float* bet  = (const float*)d_in[11];
  const float* W1   = (const float*)d_in[12];
  const float* b1   = (const float*)d_in[13];
  const float* W2   = (const float*)d_in[14];
  const float* b2   = (const float*)d_in[15];

  char* ws = (char*)d_ws;
  size_t off = 0;
  auto alloc = [&](size_t bytes) {
    void* p = ws + off;
    off = (off + bytes + 255) & ~(size_t)255;
    return p;
  };
  int* cnt     = (int*)alloc((size_t)NL_NN * 4);
  int* rowptr  = (int*)alloc((size_t)(NL_NN + 1) * 4);
  int* btot    = (int*)alloc(SCAN_BLKS * 4);
  int* boff    = (int*)alloc(SCAN_BLKS * 4);
  int2* ep     = (int2*)alloc((size_t)N_LAYERS * N_EDGES * 8);
  float* out_pre = (float*)alloc((size_t)N_LAYERS * N_NODES * 32 * 4);
  float* gsum   = (float*)alloc(N_LAYERS * 32 * 4);
  float* gsumsq = (float*)alloc(N_LAYERS * 32 * 4);
  unsigned short* xlb = (unsigned short*)alloc((size_t)NL_NN * 64 * 2);  // 64 MB
  unsigned short* xrb = (unsigned short*)alloc((size_t)NL_NN * 64 * 2);  // 64 MB
  __hip_bfloat16* w1t = (__hip_bfloat16*)alloc((size_t)896 * 800 * 2);
  __hip_bfloat16* hn  = (__hip_bfloat16*)xlb;      // alias: xlb dead after attn
  __hip_bfloat16* h1b = (__hip_bfloat16*)out_pre;  // alias: out_pre dead after norm

  hipMemsetAsync(gsum, 0, N_LAYERS * 32 * 4, stream);
  hipMemsetAsync(gsumsq, 0, N_LAYERS * 32 * 4, stream);

  count_kernel<<<N_LAYERS * 2, 1024, 0, stream>>>(ei, cnt);
  scan_a<<<SCAN_BLKS, 1024, 0, stream>>>(cnt, rowptr, btot);
  scan_b<<<1, 512, 0, stream>>>(btot, boff);
  scan_c<<<SCAN_BLKS, 1024, 0, stream>>>(rowptr, boff);
  fill_kernel<<<N_LAYERS * 2, 1024, 0, stream>>>(ei, ew, rowptr, ep);
  xlr_kernel<<<NL_NN / 4, 256, 0, stream>>>(x, Wl, bl, Wr, br, xlb, xrb);
  attn_kernel<<<NL_NN / 4, 256, 0, stream>>>(
      xlb, xrb, rowptr, ep, We, att, cb, out_pre);
  stats_kernel<<<N_LAYERS * 16, 256, 0, stream>>>(out_pre, gsum, gsumsq);
  norm_kernel<<<(NL_NN * 8) / 256, 256, 0, stream>>>(
      out_pre, gsum, gsumsq, gam, bet, hn);
  w1t_kernel<<<dim3(28, 25), dim3(32, 8), 0, stream>>>(W1, w1t);
  gemm1_kernel<<<dim3(7, 157), 256, 0, stream>>>(
      (const short*)hn, (const short*)w1t, b1, h1b);
  gemm2_kernel<<<5000, 256, 0, stream>>>(h1b, W2, b2, (float*)d_out);
}

// Round 8
// 669.931 us; speedup vs baseline: 1.9114x; 1.0567x over previous
//
#include <hip/hip_runtime.h>
#include <hip/hip_bf16.h>

#define N_NODES 20000
#define N_EDGES 100000
#define N_LAYERS 25
#define NPAD 20096   // 157*128
#define EPS_BN 1e-5f
#define LOG2E 1.44269504088896340736f
#define NL_NN (N_LAYERS * N_NODES)          // 500000
#define TOTAL_E (N_LAYERS * N_EDGES)        // 2500000
#define SCAN_BLKS ((NL_NN + 1023) / 1024)   // 489
#define HALF_N 10000
#define XLR_BASE 50
#define XLR_BLKS (NL_NN / 16)               // 31250
#define W1T_BASE (XLR_BASE + XLR_BLKS)      // 31300
#define PREP_BLKS (W1T_BASE + 700)          // 32000

typedef short short8 __attribute__((ext_vector_type(8)));
typedef short short4v __attribute__((ext_vector_type(4)));
typedef float floatx4 __attribute__((ext_vector_type(4)));

template <int PAT>
__device__ __forceinline__ float swz(float v) {
  return __int_as_float(__builtin_amdgcn_ds_swizzle(__float_as_int(v), PAT));
}

template <int CTRL>
__device__ __forceinline__ float dpp_add(float v) {
  int r = __builtin_amdgcn_update_dpp(0, __float_as_int(v), CTRL, 0xF, 0xF, true);
  return v + __int_as_float(r);
}

__device__ __forceinline__ float ldbf(const unsigned short* __restrict__ p, size_t idx) {
  return __uint_as_float((unsigned)p[idx] << 16);
}

__device__ __forceinline__ unsigned short bfbits(float v) {
  return __builtin_bit_cast(unsigned short, (__hip_bfloat16)v);
}

// ---------------- prep: count (LDS histogram) + xlr + w1t, one dispatch -----
__global__ __launch_bounds__(1024) void prep_kernel(
    const int* __restrict__ ei, const float* __restrict__ x,
    const float* __restrict__ Wl, const float* __restrict__ bl,
    const float* __restrict__ Wr, const float* __restrict__ br,
    const float* __restrict__ W1, int* __restrict__ cnt,
    unsigned short* __restrict__ xlb, unsigned short* __restrict__ xrb,
    __hip_bfloat16* __restrict__ W1bT) {
  __shared__ int smem[HALF_N];  // 40 KB (count); w1t reuses as float tile
  int b = blockIdx.x;
  if (b < XLR_BASE) {
    int l = b >> 1, half = b & 1, base = half * HALF_N;
    for (int i = threadIdx.x; i < HALF_N; i += 1024) smem[i] = 0;
    __syncthreads();
    const int* dstp = ei + (size_t)l * 2 * N_EDGES + N_EDGES;
    for (int e = threadIdx.x; e < N_EDGES; e += 1024) {
      int d = dstp[e] - base;
      if ((unsigned)d < (unsigned)HALF_N) atomicAdd(&smem[d], 1);
    }
    __syncthreads();
    int* outp = cnt + l * N_NODES + base;
    for (int i = threadIdx.x; i < HALF_N; i += 1024) outp[i] = smem[i];
  } else if (b < W1T_BASE) {
    int wid = (b - XLR_BASE) * 16 + (threadIdx.x >> 6);
    int lane = threadIdx.x & 63;
    int l = wid / N_NODES, n = wid - l * N_NODES;
    float a = bl[l * 64 + lane];
    float c = br[l * 64 + lane];
#pragma unroll
    for (int k = 0; k < 5; k++) {
      float xk = x[n * 5 + k];
      a = fmaf(xk, Wl[(l * 5 + k) * 64 + lane], a);
      c = fmaf(xk, Wr[(l * 5 + k) * 64 + lane], c);
    }
    xlb[(size_t)wid * 64 + lane] = bfbits(a);
    xrb[(size_t)wid * 64 + lane] = bfbits(c);
  } else {
    float* tile = (float*)smem;  // [32][33]
    int bb = b - W1T_BASE;
    int j0 = (bb % 28) * 32, k0 = (bb / 28) * 32;
    int tx = threadIdx.x & 31, ty = threadIdx.x >> 5;
    tile[ty * 33 + tx] = (j0 + tx < 800) ? W1[(k0 + ty) * 800 + j0 + tx] : 0.f;
    __syncthreads();
    W1bT[(size_t)(j0 + ty) * 800 + k0 + tx] = (__hip_bfloat16)tile[tx * 33 + ty];
  }
}

// ---------------- flat decoupled scan over 500K counts ----------------
__global__ __launch_bounds__(1024) void scan_a(const int* __restrict__ cnt,
                                               int* __restrict__ scn,
                                               int* __restrict__ btot) {
  int t = threadIdx.x, b = blockIdx.x;
  int i = b * 1024 + t;
  int lane = t & 63, wv = t >> 6;
  int v = (i < NL_NN) ? cnt[i] : 0;
  int sc = v;
#pragma unroll
  for (int off = 1; off < 64; off <<= 1) {
    int u = __shfl_up(sc, off);
    if (lane >= off) sc += u;
  }
  __shared__ int ws[16];
  if (lane == 63) ws[wv] = sc;
  __syncthreads();
  if (t < 16) {
    int xx = ws[t];
#pragma unroll
    for (int off = 1; off < 16; off <<= 1) {
      int u = __shfl_up(xx, off);
      if (t >= off) xx += u;
    }
    ws[t] = xx;
  }
  __syncthreads();
  int bofs = wv ? ws[wv - 1] : 0;
  if (i < NL_NN) scn[i] = bofs + sc - v;  // exclusive within block
  if (t == 0) btot[b] = ws[15];
}

// scan_b also zeroes gsum/gsumsq (replaces two memset dispatches)
__global__ __launch_bounds__(512) void scan_b(const int* __restrict__ btot,
                                              int* __restrict__ boff,
                                              float* __restrict__ gsum,
                                              float* __restrict__ gsumsq) {
  int t = threadIdx.x;
  for (int i = t; i < N_LAYERS * 32; i += 512) {
    gsum[i] = 0.f;
    gsumsq[i] = 0.f;
  }
  int lane = t & 63, wv = t >> 6;
  int v = (t < SCAN_BLKS) ? btot[t] : 0;
  int sc = v;
#pragma unroll
  for (int off = 1; off < 64; off <<= 1) {
    int u = __shfl_up(sc, off);
    if (lane >= off) sc += u;
  }
  __shared__ int ws[8];
  if (lane == 63) ws[wv] = sc;
  __syncthreads();
  if (t < 8) {
    int xx = ws[t];
#pragma unroll
    for (int off = 1; off < 8; off <<= 1) {
      int u = __shfl_up(xx, off);
      if (t >= off) xx += u;
    }
    ws[t] = xx;
  }
  __syncthreads();
  int bofs = wv ? ws[wv - 1] : 0;
  if (t < SCAN_BLKS) boff[t] = bofs + sc - v;
}

// ---------------- fill: LDS position counters (seeded scn+boff) -------------
__global__ __launch_bounds__(1024) void fill_kernel(const int* __restrict__ ei,
                                                    const float* __restrict__ ew,
                                                    const int* __restrict__ scn,
                                                    const int* __restrict__ boff,
                                                    int2* __restrict__ ep) {
  __shared__ int off[HALF_N];  // global positions
  int l = blockIdx.x >> 1, half = blockIdx.x & 1;
  int base = half * HALF_N;
  for (int i = threadIdx.x; i < HALF_N; i += 1024) {
    int gi = l * N_NODES + base + i;
    off[i] = scn[gi] + boff[gi >> 10];
  }
  __syncthreads();
  const int* srcp = ei + (size_t)l * 2 * N_EDGES;
  const int* dstp = srcp + N_EDGES;
  const float* ewp = ew + (size_t)l * N_EDGES;
  for (int e = threadIdx.x; e < N_EDGES; e += 1024) {
    int d = dstp[e] - base;
    if ((unsigned)d < (unsigned)HALF_N) {
      int pos = atomicAdd(&off[d], 1);
      int2 rec;
      rec.x = srcp[e];
      rec.y = __float_as_int(ewp[e]);
      ep[pos] = rec;
    }
  }
}

// ---------------- fused GAT layer (1 wave per (layer,node), paired edges) ----
__global__ __launch_bounds__(256) void attn_kernel(
    const unsigned short* __restrict__ xlg, const unsigned short* __restrict__ xrg,
    const int* __restrict__ scn, const int* __restrict__ boff,
    const int2* __restrict__ ep,
    const float* __restrict__ We, const float* __restrict__ att,
    const float* __restrict__ cbias, unsigned short* __restrict__ out_pre) {
  int wid = blockIdx.x * 4 + (threadIdx.x >> 6);
  int lane = threadIdx.x & 63;
  int l = wid / N_NODES, n = wid - l * N_NODES;

  const unsigned short* xlb = xlg + (size_t)l * N_NODES * 64;
  float wev = We[l * 64 + lane];
  float att2v = att[l * 64 + lane] * LOG2E;

  float xrn = ldbf(xrg, (size_t)wid * 64 + lane);
  float xln = ldbf(xlb, (size_t)n * 64 + lane);

  int start = __builtin_amdgcn_readfirstlane(scn[wid] + boff[wid >> 10]);
  int ip = wid + 1;
  int end = (ip == NL_NN)
                ? TOTAL_E
                : __builtin_amdgcn_readfirstlane(scn[ip] + boff[ip >> 10]);
  int cnt = end - start;
  int cnt64 = cnt < 64 ? cnt : 64;

  // batch-load up to 64 edge records: lane e holds ep[start+e]; others 0
  int rsrc = 0, rw = 0;
  if (lane < cnt64) {
    int2 rec = ep[start + lane];
    rsrc = rec.x;
    rw = rec.y;
  }

  // ewsum once per node (inactive lanes hold 0)
  float ewsum = __int_as_float(rw);
  ewsum = dpp_add<0xB1>(ewsum);
  ewsum = dpp_add<0x4E>(ewsum);
  ewsum = dpp_add<0x141>(ewsum);
  ewsum = dpp_add<0x140>(ewsum);
  ewsum += swz<0x401F>(ewsum);
  ewsum += __shfl_xor(ewsum, 32);

  float ssum = 0.f, acc = 0.f;

  if (cnt64 > 0) {
    int sA = __builtin_amdgcn_readlane(rsrc, 0);
    int sB = __builtin_amdgcn_readlane(rsrc, 1 & 63);
    float xa = ldbf(xlb, (size_t)sA * 64 + lane);
    float xb = ldbf(xlb, (size_t)sB * 64 + lane);
    for (int e = 0; e < cnt64; e += 2) {
      int sC = __builtin_amdgcn_readlane(rsrc, (e + 2) & 63);
      int sD = __builtin_amdgcn_readlane(rsrc, (e + 3) & 63);
      float xc = ldbf(xlb, (size_t)sC * 64 + lane);
      float xd = ldbf(xlb, (size_t)sD * 64 + lane);
      float w0 = __int_as_float(__builtin_amdgcn_readlane(rw, e));
      float w1 = __int_as_float(__builtin_amdgcn_readlane(rw, (e + 1) & 63));
      float v0 = xa + fmaf(w0, wev, xrn);
      float v1 = xb + fmaf(w1, wev, xrn);
      float lk0 = fmaxf(v0, 0.2f * v0);
      float lk1 = fmaxf(v1, 0.2f * v1);
      float p0 = lk0 * att2v;
      float p1 = lk1 * att2v;
      p0 = dpp_add<0xB1>(p0);  p1 = dpp_add<0xB1>(p1);
      p0 = dpp_add<0x4E>(p0);  p1 = dpp_add<0x4E>(p1);
      p0 = dpp_add<0x141>(p0); p1 = dpp_add<0x141>(p1);
      p0 = dpp_add<0x140>(p0); p1 = dpp_add<0x140>(p1);
      p0 += swz<0x401F>(p0);   p1 += swz<0x401F>(p1);
      float pe0 = __builtin_amdgcn_exp2f(p0);
      float pe1 = __builtin_amdgcn_exp2f(p1);
      ssum += pe0;
      acc = fmaf(xa, pe0, acc);
      if (e + 1 < cnt64) {  // uniform branch
        ssum += pe1;
        acc = fmaf(xb, pe1, acc);
      }
      xa = xc;
      xb = xd;
    }
  }
  // rare overflow path: in-degree > 64
  for (int e = start + 64; e < end; e++) {
    int2 rec = ep[e];
    int s = __builtin_amdgcn_readfirstlane(rec.x);
    float w = __int_as_float(__builtin_amdgcn_readfirstlane(rec.y));
    float xg = ldbf(xlb, (size_t)s * 64 + lane);
    float v = xg + fmaf(w, wev, xrn);
    float lk = fmaxf(v, 0.2f * v);
    float p = lk * att2v;
    p = dpp_add<0xB1>(p);
    p = dpp_add<0x4E>(p);
    p = dpp_add<0x141>(p);
    p = dpp_add<0x140>(p);
    p += swz<0x401F>(p);
    float pe = __builtin_amdgcn_exp2f(p);
    ssum += pe;
    acc = fmaf(xg, pe, acc);
    ewsum += w;
  }
  // self loop: attr = mean of incoming edge attrs
  {
    float w = ewsum * __builtin_amdgcn_rcpf(fmaxf((float)cnt, 1.f));
    float v = xln + fmaf(w, wev, xrn);
    float lk = fmaxf(v, 0.2f * v);
    float p = lk * att2v;
    p = dpp_add<0xB1>(p);
    p = dpp_add<0x4E>(p);
    p = dpp_add<0x141>(p);
    p = dpp_add<0x140>(p);
    p += swz<0x401F>(p);
    float pe = __builtin_amdgcn_exp2f(p);
    ssum += pe;
    acc = fmaf(xln, pe, acc);
  }
  float outv = acc * __builtin_amdgcn_rcpf(ssum * (float)(cnt + 1));
  float o2 = outv + __shfl_xor(outv, 32);
  if (lane < 32)
    out_pre[(size_t)wid * 32 + lane] = bfbits(0.5f * o2 + cbias[l * 32 + lane]);
}

// ---------------- BatchNorm stats (bf16 input) ----------------
__global__ __launch_bounds__(256) void stats_kernel(const unsigned short* __restrict__ out_pre,
                                                    float* __restrict__ gsum,
                                                    float* __restrict__ gsumsq) {
  int l = blockIdx.x >> 4, chunk = blockIdx.x & 15;
  int t = threadIdx.x;
  int c = t & 31, nsub = t >> 5;
  int n0 = chunk * 1250;
  float s1 = 0.f, s2 = 0.f;
  for (int n = n0 + nsub; n < n0 + 1250; n += 8) {
    float v = ldbf(out_pre, ((size_t)l * N_NODES + n) * 32 + c);
    s1 += v; s2 += v * v;
  }
  __shared__ float l1[256], l2[256];
  l1[t] = s1; l2[t] = s2;
  __syncthreads();
  for (int off = 128; off >= 32; off >>= 1) {
    if (t < off) { l1[t] += l1[t + off]; l2[t] += l2[t + off]; }
    __syncthreads();
  }
  if (t < 32) {
    atomicAdd(&gsum[l * 32 + t], l1[t]);
    atomicAdd(&gsumsq[l * 32 + t], l2[t]);
  }
}

// ---------------- normalize + leaky relu -> bf16 [L][NPAD][32] ----------------
__global__ __launch_bounds__(256) void norm_kernel(const unsigned short* __restrict__ out_pre,
                                                   const float* __restrict__ gsum,
                                                   const float* __restrict__ gsumsq,
                                                   const float* __restrict__ gamma,
                                                   const float* __restrict__ beta,
                                                   unsigned short* __restrict__ hn) {
  int idx = blockIdx.x * 256 + threadIdx.x;  // < 25*20000*8
  int l = idx / (N_NODES * 8);
  int rem = idx - l * (N_NODES * 8);
  int n = rem >> 3, q = rem & 7;
  int c0 = q * 4;
  short4v v4 = *(const short4v*)(out_pre + ((size_t)l * N_NODES + n) * 32 + c0);
  short4v o;
#pragma unroll
  for (int i = 0; i < 4; i++) {
    int c = c0 + i;
    float mu = gsum[l * 32 + c] * (1.f / N_NODES);
    float var = gsumsq[l * 32 + c] * (1.f / N_NODES) - mu * mu;
    float vv = __uint_as_float((unsigned)(unsigned short)v4[i] << 16);
    float v = gamma[l * 32 + c] * (vv - mu) * rsqrtf(var + EPS_BN) + beta[l * 32 + c];
    v = v > 0.f ? v : 0.01f * v;
    o[i] = (short)bfbits(v);
  }
  *(short4v*)(hn + ((size_t)l * NPAD + n) * 32 + c0) = o;
}

// ---------------- GEMM1: h[NPAD x 800] @ W1 -> relu -> bf16 h1 ----------------
__global__ __launch_bounds__(256) void gemm1_kernel(const short* __restrict__ hn,
                                                    const short* __restrict__ W1bT,
                                                    const float* __restrict__ b1,
                                                    __hip_bfloat16* __restrict__ h1b) {
  __shared__ __align__(16) short As[128 * 40];
  __shared__ __align__(16) short Bs[128 * 40];
  int t = threadIdx.x;
  int n0 = blockIdx.x * 128, m0 = blockIdx.y * 128;
  int wave = t >> 6, lane = t & 63;
  int wr = wave >> 1, wc = wave & 1;
  int mrow = lane & 15, quad = lane >> 4;
  floatx4 acc[4][4];
#pragma unroll
  for (int i = 0; i < 4; i++)
#pragma unroll
    for (int j = 0; j < 4; j++) acc[i][j] = (floatx4){0.f, 0.f, 0.f, 0.f};

  int r0 = t >> 2, s0 = t & 3;
  int r1 = (t + 256) >> 2, s1 = (t + 256) & 3;
  const short* aB0 = hn + (size_t)(m0 + r0) * 32 + s0 * 8;
  const short* aB1 = hn + (size_t)(m0 + r1) * 32 + s1 * 8;
  const short* bB0 = W1bT + (size_t)(n0 + r0) * 800 + s0 * 8;
  const short* bB1 = W1bT + (size_t)(n0 + r1) * 800 + s1 * 8;
  const size_t ak = (size_t)NPAD * 32;

  int4 pa0 = *(const int4*)aB0;
  int4 pa1 = *(const int4*)aB1;
  int4 pb0 = *(const int4*)bB0;
  int4 pb1 = *(const int4*)bB1;

  for (int kt = 0; kt < 25; kt++) {
    *(int4*)(&As[r0 * 40 + s0 * 8]) = pa0;
    *(int4*)(&As[r1 * 40 + s1 * 8]) = pa1;
    *(int4*)(&Bs[r0 * 40 + s0 * 8]) = pb0;
    *(int4*)(&Bs[r1 * 40 + s1 * 8]) = pb1;
    __syncthreads();
    int ktn = kt < 24 ? kt + 1 : 24;  // last-iter loads valid but unused
    pa0 = *(const int4*)(aB0 + (size_t)ktn * ak);
    pa1 = *(const int4*)(aB1 + (size_t)ktn * ak);
    pb0 = *(const int4*)(bB0 + ktn * 32);
    pb1 = *(const int4*)(bB1 + ktn * 32);
    short8 af[4], bfr[4];
#pragma unroll
    for (int i = 0; i < 4; i++)
      af[i] = *(const short8*)(&As[(wr * 64 + i * 16 + mrow) * 40 + quad * 8]);
#pragma unroll
    for (int j = 0; j < 4; j++)
      bfr[j] = *(const short8*)(&Bs[(wc * 64 + j * 16 + mrow) * 40 + quad * 8]);
#pragma unroll
    for (int i = 0; i < 4; i++)
#pragma unroll
      for (int j = 0; j < 4; j++)
        acc[i][j] = __builtin_amdgcn_mfma_f32_16x16x32_bf16(af[i], bfr[j], acc[i][j], 0, 0, 0);
    __syncthreads();
  }

#pragma unroll
  for (int i = 0; i < 4; i++) {
#pragma unroll
    for (int j = 0; j < 4; j++) {
#pragma unroll
      for (int r = 0; r < 4; r++) {
        int row = m0 + wr * 64 + i * 16 + quad * 4 + r;
        int col = n0 + wc * 64 + j * 16 + mrow;
        if (col < 800) {
          float v = acc[i][j][r] + b1[col];
          v = fmaxf(v, 0.f);
          h1b[(size_t)row * 800 + col] = (__hip_bfloat16)v;
        }
      }
    }
  }
}

// ---------------- GEMM2: h1[20000 x 800] @ W2[800 x 5] + b2 ----------------
__global__ __launch_bounds__(256) void gemm2_kernel(const __hip_bfloat16* __restrict__ h1b,
                                                    const float* __restrict__ W2,
                                                    const float* __restrict__ b2,
                                                    float* __restrict__ out) {
  int wid = blockIdx.x * 4 + (threadIdx.x >> 6);
  int lane = threadIdx.x & 63;
  if (wid >= N_NODES) return;
  const __hip_bfloat16* row = h1b + (size_t)wid * 800;
  float a[5] = {0.f, 0.f, 0.f, 0.f, 0.f};
  for (int k = lane * 2; k < 800; k += 128) {
    float a0 = (float)row[k], a1 = (float)row[k + 1];
#pragma unroll
    for (int j = 0; j < 5; j++) a[j] += a0 * W2[k * 5 + j] + a1 * W2[(k + 1) * 5 + j];
  }
#pragma unroll
  for (int j = 0; j < 5; j++) {
    a[j] += __shfl_xor(a[j], 32);
    a[j] += __shfl_xor(a[j], 16);
    a[j] += __shfl_xor(a[j], 8);
    a[j] += __shfl_xor(a[j], 4);
    a[j] += __shfl_xor(a[j], 2);
    a[j] += __shfl_xor(a[j], 1);
  }
  if (lane == 0) {
#pragma unroll
    for (int j = 0; j < 5; j++) out[wid * 5 + j] = a[j] + b2[j];
  }
}

extern "C" void kernel_launch(void* const* d_in, const int* in_sizes, int n_in,
                              void* d_out, int out_size, void* d_ws, size_t ws_size,
                              hipStream_t stream) {
  const float* x    = (const float*)d_in[0];
  const int*   ei   = (const int*)d_in[1];
  const float* ew   = (const float*)d_in[2];
  const float* Wl   = (const float*)d_in[3];
  const float* bl   = (const float*)d_in[4];
  const float* Wr   = (const float*)d_in[5];
  const float* br   = (const float*)d_in[6];
  const float* We   = (const float*)d_in[7];
  const float* att  = (const float*)d_in[8];
  const float* cb   = (const float*)d_in[9];
  const float* gam  = (const float*)d_in[10];
  const float* bet  = (const float*)d_in[11];
  const float* W1   = (const float*)d_in[12];
  const float* b1   = (const float*)d_in[13];
  const float* W2   = (const float*)d_in[14];
  const float* b2   = (const float*)d_in[15];

  char* ws = (char*)d_ws;
  size_t off = 0;
  auto alloc = [&](size_t bytes) {
    void* p = ws + off;
    off = (off + bytes + 255) & ~(size_t)255;
    return p;
  };
  int* cnt     = (int*)alloc((size_t)NL_NN * 4);
  int* scn     = (int*)alloc((size_t)(NL_NN + 1) * 4);
  int* btot    = (int*)alloc(SCAN_BLKS * 4);
  int* boff    = (int*)alloc(SCAN_BLKS * 4);
  int2* ep     = (int2*)alloc((size_t)TOTAL_E * 8);
  unsigned short* out_pre = (unsigned short*)alloc((size_t)NL_NN * 32 * 2);  // 32 MB bf16
  float* gsum   = (float*)alloc(N_LAYERS * 32 * 4);
  float* gsumsq = (float*)alloc(N_LAYERS * 32 * 4);
  unsigned short* xlb = (unsigned short*)alloc((size_t)NL_NN * 64 * 2);  // 64 MB
  unsigned short* xrb = (unsigned short*)alloc((size_t)NL_NN * 64 * 2);  // 64 MB
  __hip_bfloat16* w1t = (__hip_bfloat16*)alloc((size_t)896 * 800 * 2);
  unsigned short* hn  = (unsigned short*)xlb;      // alias: xlb dead after attn
  __hip_bfloat16* h1b = (__hip_bfloat16*)xrb;      // alias: xrb dead after attn

  prep_kernel<<<PREP_BLKS, 1024, 0, stream>>>(ei, x, Wl, bl, Wr, br, W1,
                                              cnt, xlb, xrb, w1t);
  scan_a<<<SCAN_BLKS, 1024, 0, stream>>>(cnt, scn, btot);
  scan_b<<<1, 512, 0, stream>>>(btot, boff, gsum, gsumsq);
  fill_kernel<<<N_LAYERS * 2, 1024, 0, stream>>>(ei, ew, scn, boff, ep);
  attn_kernel<<<NL_NN / 4, 256, 0, stream>>>(
      xlb, xrb, scn, boff, ep, We, att, cb, out_pre);
  stats_kernel<<<N_LAYERS * 16, 256, 0, stream>>>(out_pre, gsum, gsumsq);
  norm_kernel<<<(NL_NN * 8) / 256, 256, 0, stream>>>(
      out_pre, gsum, gsumsq, gam, bet, hn);
  gemm1_kernel<<<dim3(7, 157), 256, 0, stream>>>(
      (const short*)hn, (const short*)w1t, b1, h1b);
  gemm2_kernel<<<5000, 256, 0, stream>>>(h1b, W2, b2, (float*)d_out);
}